// Round 9
// baseline (457.108 us; speedup 1.0000x reference)
//
#include <hip/hip_runtime.h>
#include <hip/hip_fp16.h>

#define FDIM 64
#define EPS 1e-5f
#define NBUCK 1024     // coarse buckets = high bits of 17-bit id
#define LOWB 7
#define LOWMASK 127
#define RB 256         // radix blocks
#define RT 1024        // radix threads per block

// ---------------- per-block coarse histograms of src>>7 and dst>>7 ----------------
__global__ void k_hist(const int* __restrict__ src, const int* __restrict__ dst,
                       int* __restrict__ histS, int* __restrict__ histD, int E, int chunk) {
    __shared__ int hs[NBUCK], hd[NBUCK];
    int tid = threadIdx.x;            // RT == NBUCK == 1024
    hs[tid] = 0; hd[tid] = 0;
    __syncthreads();
    int b = blockIdx.x;
    int beg = b * chunk;
    int end = min(E, beg + chunk);
    int i = beg + tid * 4;
    for (; i + 3 < end; i += RT * 4) {
        int4 s = *(const int4*)(src + i);
        int4 d = *(const int4*)(dst + i);
        atomicAdd(&hs[s.x >> LOWB], 1); atomicAdd(&hd[d.x >> LOWB], 1);
        atomicAdd(&hs[s.y >> LOWB], 1); atomicAdd(&hd[d.y >> LOWB], 1);
        atomicAdd(&hs[s.z >> LOWB], 1); atomicAdd(&hd[d.z >> LOWB], 1);
        atomicAdd(&hs[s.w >> LOWB], 1); atomicAdd(&hd[d.w >> LOWB], 1);
    }
    if (i < end) {
        for (int j = i; j < end && j < i + 4; ++j) {
            atomicAdd(&hs[src[j] >> LOWB], 1);
            atomicAdd(&hd[dst[j] >> LOWB], 1);
        }
    }
    __syncthreads();
    histS[b * NBUCK + tid] = hs[tid];
    histD[b * NBUCK + tid] = hd[tid];
}

// ---------------- scan the [RB][NBUCK] matrix -> per-block offsets + bucket bases ----------------
__global__ void k_scan(int* __restrict__ histS, int* __restrict__ baseS,
                       int* __restrict__ histD, int* __restrict__ baseD, int B) {
    int* hist = (blockIdx.x == 0) ? histS : histD;
    int* base = (blockIdx.x == 0) ? baseS : baseD;
    __shared__ int s[NBUCK];
    int k = threadIdx.x;
    int run = 0;
    for (int b = 0; b < B; b += 8) {     // B % 8 == 0; 8 independent loads per round
        int t[8];
#pragma unroll
        for (int q = 0; q < 8; ++q) t[q] = hist[(b + q) * NBUCK + k];
#pragma unroll
        for (int q = 0; q < 8; ++q) { hist[(b + q) * NBUCK + k] = run; run += t[q]; }
    }
    s[k] = run;
    __syncthreads();
    for (int off = 1; off < NBUCK; off <<= 1) {
        int t = (k >= off) ? s[k - off] : 0;
        __syncthreads();
        s[k] += t;
        __syncthreads();
    }
    int excl = (k > 0) ? s[k - 1] : 0;
    base[k] = excl;
    if (k == NBUCK - 1) base[NBUCK] = s[NBUCK - 1];
    for (int b = 0; b < B; ++b)
        hist[b * NBUCK + k] += excl;
}

// ---------------- coarse partition: LDS cursors per block, no global atomics ----------------
__global__ void k_bucket(const int* __restrict__ src, const int* __restrict__ dst,
                         const int* __restrict__ histS, const int* __restrict__ histD,
                         unsigned char* __restrict__ tmpS, int* __restrict__ tmpD,
                         int E, int chunk) {
    __shared__ int curS[NBUCK], curD[NBUCK];
    int tid = threadIdx.x;
    int b = blockIdx.x;
    curS[tid] = histS[b * NBUCK + tid];
    curD[tid] = histD[b * NBUCK + tid];
    __syncthreads();
    int beg = b * chunk;
    int end = min(E, beg + chunk);
    int i = beg + tid * 4;
    for (; i + 3 < end; i += RT * 4) {
        int4 s = *(const int4*)(src + i);
        int4 d = *(const int4*)(dst + i);
        int p;
        p = atomicAdd(&curS[s.x >> LOWB], 1); tmpS[p] = (unsigned char)(s.x & LOWMASK);
        p = atomicAdd(&curS[s.y >> LOWB], 1); tmpS[p] = (unsigned char)(s.y & LOWMASK);
        p = atomicAdd(&curS[s.z >> LOWB], 1); tmpS[p] = (unsigned char)(s.z & LOWMASK);
        p = atomicAdd(&curS[s.w >> LOWB], 1); tmpS[p] = (unsigned char)(s.w & LOWMASK);
        p = atomicAdd(&curD[d.x >> LOWB], 1); tmpD[p] = (s.x << LOWB) | (d.x & LOWMASK);
        p = atomicAdd(&curD[d.y >> LOWB], 1); tmpD[p] = (s.y << LOWB) | (d.y & LOWMASK);
        p = atomicAdd(&curD[d.z >> LOWB], 1); tmpD[p] = (s.z << LOWB) | (d.z & LOWMASK);
        p = atomicAdd(&curD[d.w >> LOWB], 1); tmpD[p] = (s.w << LOWB) | (d.w & LOWMASK);
    }
    if (i < end) {
        for (int j = i; j < end && j < i + 4; ++j) {
            int sv = src[j], dv = dst[j];
            int p = atomicAdd(&curS[sv >> LOWB], 1);
            tmpS[p] = (unsigned char)(sv & LOWMASK);
            p = atomicAdd(&curD[dv >> LOWB], 1);
            tmpD[p] = (sv << LOWB) | (dv & LOWMASK);
        }
    }
}

// ---------------- merged fine pass (one dispatch, two jobs running concurrently) ------
// blocks [0, nbuck):       per-bucket fine hist+scan -> rowptr, LDS-cursor scatter -> csr_src
// blocks [nbuck, 2*nbuck): per-bucket src hist -> degO + scale x rows -> bufA (half)
__global__ void k_fine(const int* __restrict__ tmpD, const int* __restrict__ baseD,
                       int* __restrict__ csr_src, int* __restrict__ rowptr,
                       const unsigned char* __restrict__ tmpS, const int* __restrict__ baseS,
                       int* __restrict__ degO, const float* __restrict__ x,
                       __half* __restrict__ bufA, int N, int nbuck) {
    __shared__ int hist[128];
    __shared__ int scanv[128];
    int tid = threadIdx.x;
    if (blockIdx.x < nbuck) {
        int b = blockIdx.x;
        int s0 = baseD[b];
        int s1 = baseD[b + 1];
        if (tid < 128) hist[tid] = 0;
        __syncthreads();
        for (int i = s0 + tid; i < s1; i += 256)
            atomicAdd(&hist[tmpD[i] & LOWMASK], 1);
        __syncthreads();
        int mine = (tid < 128) ? hist[tid] : 0;
        if (tid < 128) scanv[tid] = mine;
        __syncthreads();
        for (int off = 1; off < 128; off <<= 1) {
            int t = (tid < 128 && tid >= off) ? scanv[tid - off] : 0;
            __syncthreads();
            if (tid < 128) scanv[tid] += t;
            __syncthreads();
        }
        if (tid < 128) {
            int excl = scanv[tid] - mine;       // exclusive scan
            int d = (b << LOWB) + tid;
            if (d <= N) rowptr[d] = s0 + excl;  // covers rowptr[N]=E too
            hist[tid] = excl;                   // LDS cursors
        }
        __syncthreads();
        for (int i = s0 + tid; i < s1; i += 256) {
            int p = tmpD[i];
            int pos = atomicAdd(&hist[p & LOWMASK], 1);
            csr_src[s0 + pos] = p >> LOWB;
        }
    } else {
        int b = blockIdx.x - nbuck;
        int s0 = baseS[b];
        int s1 = baseS[b + 1];
        if (tid < 128) hist[tid] = 0;
        __syncthreads();
        for (int i = s0 + tid; i < s1; i += 256)
            atomicAdd(&hist[tmpS[i]], 1);
        __syncthreads();
        if (tid < 128) {
            int d = (b << LOWB) + tid;
            if (d < N) degO[d] = hist[tid];
        }
        // scale x rows for this bucket's 128 nodes: thread = (node, half-row part)
        int node = (b << LOWB) + (tid >> 1);
        if (node < N) {
            float rs = rsqrtf((float)max(hist[tid >> 1], 1));
            int part = tid & 1;                 // feats [part*32, part*32+32)
            const float4* xr = (const float4*)(x + (size_t)node * FDIM) + part * 8;
            float4* orow = (float4*)(bufA + (size_t)node * FDIM) + part * 4;
#pragma unroll
            for (int q = 0; q < 4; ++q) {
                float4 a = xr[2 * q];
                float4 c = xr[2 * q + 1];
                union { __half2 h[4]; float4 f; } u;
                u.h[0] = __floats2half2_rn(a.x * rs, a.y * rs);
                u.h[1] = __floats2half2_rn(a.z * rs, a.w * rs);
                u.h[2] = __floats2half2_rn(c.x * rs, c.y * rs);
                u.h[3] = __floats2half2_rn(c.z * rs, c.w * rs);
                orow[q] = u.f;
            }
        }
    }
}

// ---------------- CSR SpMM: 8 rows per wave, 16B/lane slices, fp32 acc ----------------
__global__ void k_spmm8(const __half* __restrict__ hin, const int* __restrict__ rowptr,
                        const int* __restrict__ csr_src, __half* __restrict__ out, int N) {
    int wid = (blockIdx.x * blockDim.x + threadIdx.x) >> 6;
    int lane = threadIdx.x & 63;
    int g = lane >> 3;
    int sl = lane & 7;
    int row = wid * 8 + g;
    bool rv = row < N;
    int start = rv ? rowptr[row] : 0;
    int end   = rv ? rowptr[row + 1] : 0;
    int deg = end - start;
    int md = deg;
    md = max(md, __shfl_xor(md, 8));
    md = max(md, __shfl_xor(md, 16));
    md = max(md, __shfl_xor(md, 32));
    float acc[8] = {0.f, 0.f, 0.f, 0.f, 0.f, 0.f, 0.f, 0.f};
    for (int it = 0; it < md; it += 8) {
        int a = start + it + sl;
        int ca = (a < end) ? a : ((deg > 0) ? end - 1 : 0);
        int idxv = csr_src[ca];
#pragma unroll
        for (int j = 0; j < 8; ++j) {
            int bidx = __shfl(idxv, (g << 3) + j);
            if (it + j < deg) {
                const float4* gp = (const float4*)(hin + ((size_t)bidx << 6));
                union { float4 f; __half2 h[4]; } u;
                u.f = gp[sl];
                float2 p0 = __half22float2(u.h[0]);
                float2 p1 = __half22float2(u.h[1]);
                float2 p2 = __half22float2(u.h[2]);
                float2 p3 = __half22float2(u.h[3]);
                acc[0] += p0.x; acc[1] += p0.y;
                acc[2] += p1.x; acc[3] += p1.y;
                acc[4] += p2.x; acc[5] += p2.y;
                acc[6] += p3.x; acc[7] += p3.y;
            }
        }
    }
    if (rv) {
        float rs = rsqrtf(fmaxf((float)deg, 1.0f));
        union { float4 f; __half2 h[4]; } o;
        o.h[0] = __floats2half2_rn(acc[0] * rs, acc[1] * rs);
        o.h[1] = __floats2half2_rn(acc[2] * rs, acc[3] * rs);
        o.h[2] = __floats2half2_rn(acc[4] * rs, acc[5] * rs);
        o.h[3] = __floats2half2_rn(acc[6] * rs, acc[7] * rs);
        ((float4*)(out + ((size_t)row << 6)))[sl] = o.f;
    }
}

// ---------------- register GEMM: 1 thread = 1 node; fp16 m in, fp16 h out, fp32 math ------
__global__ void k_gemm_reg(const __half* __restrict__ m, const float* __restrict__ W,
                           const float* __restrict__ b, __half* __restrict__ out, int N) {
    int n = blockIdx.x * blockDim.x + threadIdx.x;
    if (n >= N) return;
    const __half2* mrow = (const __half2*)(m + (size_t)n * FDIM);
    float acc[FDIM];
#pragma unroll
    for (int j = 0; j < FDIM; ++j) acc[j] = b[j];        // b[j] wave-uniform -> s_load
    for (int k0 = 0; k0 < FDIM; k0 += 8) {
        float2 f0 = __half22float2(mrow[(k0 >> 1) + 0]);
        float2 f1 = __half22float2(mrow[(k0 >> 1) + 1]);
        float2 f2 = __half22float2(mrow[(k0 >> 1) + 2]);
        float2 f3 = __half22float2(mrow[(k0 >> 1) + 3]);
        float mreg[8] = {f0.x, f0.y, f1.x, f1.y, f2.x, f2.y, f3.x, f3.y};
#pragma unroll
        for (int k1 = 0; k1 < 8; ++k1) {
            const float* Wrow = W + (k0 + k1) * FDIM;    // wave-uniform row -> s_load
#pragma unroll
            for (int j = 0; j < FDIM; ++j)
                acc[j] = fmaf(mreg[k1], Wrow[j], acc[j]);
        }
    }
    float4* orow = (float4*)(out + (size_t)n * FDIM);
#pragma unroll
    for (int j = 0; j < FDIM; j += 8) {
        union { __half2 h[4]; float4 f; } u;
        u.h[0] = __floats2half2_rn(acc[j + 0], acc[j + 1]);
        u.h[1] = __floats2half2_rn(acc[j + 2], acc[j + 3]);
        u.h[2] = __floats2half2_rn(acc[j + 4], acc[j + 5]);
        u.h[3] = __floats2half2_rn(acc[j + 6], acc[j + 7]);
        orow[j >> 3] = u.f;
    }
}

// ---------------- BN stats + (last block) finalize mu/coef ----------------
__global__ void k_stats_fin(const __half* __restrict__ h, float* __restrict__ ssum,
                            float* __restrict__ ssq, const float* __restrict__ g,
                            float* __restrict__ mu, float* __restrict__ coef,
                            int* __restrict__ cnt, int N) {
    __shared__ float red[256];
    __shared__ int last;
    int tid = threadIdx.x;
    int j  = tid & 63;
    int nl = tid >> 6;
    float ls = 0.f, lq = 0.f;
    int stride = gridDim.x * 4;
    for (int n = blockIdx.x * 4 + nl; n < N; n += stride) {
        float v = __half2float(h[(size_t)n * FDIM + j]);
        ls += v;
        lq += v * v;
    }
    red[tid] = ls;
    __syncthreads();
    if (nl == 0) atomicAdd(&ssum[j], red[j] + red[64 + j] + red[128 + j] + red[192 + j]);
    __syncthreads();
    red[tid] = lq;
    __syncthreads();
    if (nl == 0) atomicAdd(&ssq[j], red[j] + red[64 + j] + red[128 + j] + red[192 + j]);
    __threadfence();
    __syncthreads();
    if (tid == 0) last = (atomicAdd(cnt, 1) == (int)gridDim.x - 1);
    __syncthreads();
    if (last && tid < 64) {
        float s = __hip_atomic_load(&ssum[tid], __ATOMIC_RELAXED, __HIP_MEMORY_SCOPE_AGENT);
        float q = __hip_atomic_load(&ssq[tid],  __ATOMIC_RELAXED, __HIP_MEMORY_SCOPE_AGENT);
        float m = s / (float)N;
        float v = q / (float)N - m * m;
        mu[tid] = m;
        coef[tid] = rsqrtf(v + EPS) * g[tid];
    }
}

// ---------------- out = half(relu((h-mu)*coef+be) * rsqrt(max(degO,1))) ----------------
__global__ void k_bnrelu_scale(const float2* __restrict__ h, const float* __restrict__ mu,
                               const float* __restrict__ coef, const float* __restrict__ be,
                               const int* __restrict__ degO, float2* __restrict__ out, int n4) {
    int i = blockIdx.x * blockDim.x + threadIdx.x;
    if (i < n4) {
        int n = i >> 4;
        int j4 = (i & 15) << 2;
        float rs = rsqrtf((float)max(degO[n], 1));
        union { __half2 hh[2]; float2 f; } u;
        u.f = h[i];
        float2 v0 = __half22float2(u.hh[0]);
        float2 v1 = __half22float2(u.hh[1]);
        float r0 = fmaxf((v0.x - mu[j4 + 0]) * coef[j4 + 0] + be[j4 + 0], 0.f) * rs;
        float r1 = fmaxf((v0.y - mu[j4 + 1]) * coef[j4 + 1] + be[j4 + 1], 0.f) * rs;
        float r2 = fmaxf((v1.x - mu[j4 + 2]) * coef[j4 + 2] + be[j4 + 2], 0.f) * rs;
        float r3 = fmaxf((v1.y - mu[j4 + 3]) * coef[j4 + 3] + be[j4 + 3], 0.f) * rs;
        union { __half2 hh[2]; float2 f; } o;
        o.hh[0] = __floats2half2_rn(r0, r1);
        o.hh[1] = __floats2half2_rn(r2, r3);
        out[i] = o.f;
    }
}

// ---------------- relu(bn(h)) channel-sum + (last block) classifier ----------------
__global__ void k_bnmean_fin(const __half* __restrict__ h, const float* __restrict__ mu,
                             const float* __restrict__ coef, const float* __restrict__ be,
                             float* __restrict__ hsum, const float* __restrict__ Wc,
                             const float* __restrict__ bc, float* __restrict__ out,
                             int* __restrict__ cnt, int N) {
    __shared__ float red[256];
    __shared__ int last;
    int tid = threadIdx.x;
    int j  = tid & 63;
    int nl = tid >> 6;
    float muj = mu[j], cj = coef[j], bj = be[j];
    float ls = 0.f;
    int stride = gridDim.x * 4;
    for (int n = blockIdx.x * 4 + nl; n < N; n += stride) {
        float v = fmaxf((__half2float(h[(size_t)n * FDIM + j]) - muj) * cj + bj, 0.f);
        ls += v;
    }
    red[tid] = ls;
    __syncthreads();
    if (nl == 0) atomicAdd(&hsum[j], red[j] + red[64 + j] + red[128 + j] + red[192 + j]);
    __threadfence();
    __syncthreads();
    if (tid == 0) last = (atomicAdd(cnt, 1) == (int)gridDim.x - 1);
    __syncthreads();
    if (last) {
        if (tid < 64) {
            float hg = __hip_atomic_load(&hsum[tid], __ATOMIC_RELAXED,
                                         __HIP_MEMORY_SCOPE_AGENT) / (float)N;
            red[tid]      = hg * Wc[tid * 2 + 0];
            red[64 + tid] = hg * Wc[tid * 2 + 1];
        }
        __syncthreads();
        if (tid == 0) {
            float a = 0.f, b = 0.f;
            for (int k = 0; k < 64; ++k) { a += red[k]; b += red[64 + k]; }
            out[0] = a + bc[0];
            out[1] = b + bc[1];
        }
    }
}

extern "C" void kernel_launch(void* const* d_in, const int* in_sizes, int n_in,
                              void* d_out, int out_size, void* d_ws, size_t ws_size,
                              hipStream_t stream) {
    const float* x   = (const float*)d_in[0];
    const int*   src = (const int*)d_in[1];
    const int*   dst = (const int*)d_in[2];
    const float* W1  = (const float*)d_in[3];
    const float* b1  = (const float*)d_in[4];
    const float* g1  = (const float*)d_in[5];
    const float* be1 = (const float*)d_in[6];
    const float* W2  = (const float*)d_in[7];
    const float* b2  = (const float*)d_in[8];
    const float* g2  = (const float*)d_in[9];
    const float* be2 = (const float*)d_in[10];
    const float* Wc  = (const float*)d_in[11];
    const float* bc  = (const float*)d_in[12];
    float* out = (float*)d_out;

    const int N = in_sizes[0] / FDIM;   // 100000
    const int E = in_sizes[1];          // 1600000

    // ---- workspace layout ----
    char* w = (char*)d_ws;
    __half* bufA   = (__half*)w;                                  // N*64 halfs (12.8 MB)
    __half* bufB   = bufA + (size_t)N * FDIM;                     // N*64 halfs
    int*   csr_src = (int*)(bufB + (size_t)N * FDIM);             // E int
    int*   degO    = csr_src + E;                                 // N int
    int*   rowptr  = degO + N;                                    // N+2 int
    int*   histS   = rowptr + N + 2;                              // RB*NBUCK int
    int*   histD   = histS + RB * NBUCK;                          // RB*NBUCK int
    int*   baseS   = histD + RB * NBUCK;                          // NBUCK+1
    int*   baseD   = baseS + NBUCK + 1;                           // NBUCK+1
    float* stats   = (float*)(baseD + NBUCK + 1);                 // 1024 f } memset
    unsigned char* tmpS = (unsigned char*)(stats + 1024);         // E bytes (dedicated!)
    int*           tmpD = (int*)bufB;                             // E int, aliases bufB (dead)

    float* sum1  = stats + 0;
    float* sq1   = stats + 64;
    float* mu1   = stats + 128;
    float* coef1 = stats + 192;
    float* sum2  = stats + 256;
    float* sq2   = stats + 320;
    float* mu2   = stats + 384;
    float* coef2 = stats + 448;
    float* hsum  = stats + 512;
    int*   cnt1  = (int*)(stats + 576);
    int*   cnt2  = (int*)(stats + 577);
    int*   cnt3  = (int*)(stats + 578);

    const int n4 = N * (FDIM / 4);
    const int spmm8_blocks = ((N + 7) / 8 + 3) / 4;       // 8 rows/wave, 4 waves/block
    const int nbuck_active = (N + LOWMASK) >> LOWB;       // 782 for N=100000
    const int chunk = ((E + RB - 1) / RB + 3) & ~3;       // per-block edges, mult of 4

    hipMemsetAsync(stats, 0, 1024 * 4, stream);

    k_hist<<<RB, RT, 0, stream>>>(src, dst, histS, histD, E, chunk);
    k_scan<<<2, NBUCK, 0, stream>>>(histS, baseS, histD, baseD, RB);
    k_bucket<<<RB, RT, 0, stream>>>(src, dst, histS, histD, tmpS, tmpD, E, chunk);
    k_fine<<<2 * nbuck_active, 256, 0, stream>>>(tmpD, baseD, csr_src, rowptr,
                                                 tmpS, baseS, degO, x, bufA, N, nbuck_active);

    k_spmm8<<<spmm8_blocks, 256, 0, stream>>>(bufA, rowptr, csr_src, bufB, N);
    k_gemm_reg<<<(N + 63) / 64, 64, 0, stream>>>(bufB, W1, b1, bufA, N);
    k_stats_fin<<<512, 256, 0, stream>>>(bufA, sum1, sq1, g1, mu1, coef1, cnt1, N);
    k_bnrelu_scale<<<(n4 + 255) / 256, 256, 0, stream>>>((const float2*)bufA, mu1, coef1, be1,
                                                         degO, (float2*)bufB, n4);
    k_spmm8<<<spmm8_blocks, 256, 0, stream>>>(bufB, rowptr, csr_src, bufA, N);
    k_gemm_reg<<<(N + 63) / 64, 64, 0, stream>>>(bufA, W2, b2, bufB, N);
    k_stats_fin<<<512, 256, 0, stream>>>(bufB, sum2, sq2, g2, mu2, coef2, cnt2, N);
    k_bnmean_fin<<<512, 256, 0, stream>>>(bufB, mu2, coef2, be2, hsum, Wc, bc, out, cnt3, N);
}

// Round 10
// 408.888 us; speedup vs baseline: 1.1179x; 1.1179x over previous
//
#include <hip/hip_runtime.h>
#include <hip/hip_fp16.h>

#define FDIM 64
#define EPS 1e-5f
#define NBUCK 1024     // coarse buckets = high bits of 17-bit id
#define LOWB 7
#define LOWMASK 127
#define RB 256         // radix blocks
#define RT 1024        // radix threads per block
#define GRP 16         // rows per scan group (RB/GRP groups)

// ---------------- per-block coarse histograms of src>>7 and dst>>7 ----------------
__global__ void k_hist(const int* __restrict__ src, const int* __restrict__ dst,
                       int* __restrict__ histS, int* __restrict__ histD, int E, int chunk) {
    __shared__ int hs[NBUCK], hd[NBUCK];
    int tid = threadIdx.x;            // RT == NBUCK == 1024
    hs[tid] = 0; hd[tid] = 0;
    __syncthreads();
    int b = blockIdx.x;
    int beg = b * chunk;
    int end = min(E, beg + chunk);
    int i = beg + tid * 4;
    for (; i + 3 < end; i += RT * 4) {
        int4 s = *(const int4*)(src + i);
        int4 d = *(const int4*)(dst + i);
        atomicAdd(&hs[s.x >> LOWB], 1); atomicAdd(&hd[d.x >> LOWB], 1);
        atomicAdd(&hs[s.y >> LOWB], 1); atomicAdd(&hd[d.y >> LOWB], 1);
        atomicAdd(&hs[s.z >> LOWB], 1); atomicAdd(&hd[d.z >> LOWB], 1);
        atomicAdd(&hs[s.w >> LOWB], 1); atomicAdd(&hd[d.w >> LOWB], 1);
    }
    if (i < end) {
        for (int j = i; j < end && j < i + 4; ++j) {
            atomicAdd(&hs[src[j] >> LOWB], 1);
            atomicAdd(&hd[dst[j] >> LOWB], 1);
        }
    }
    __syncthreads();
    histS[b * NBUCK + tid] = hs[tid];
    histD[b * NBUCK + tid] = hd[tid];
}

// ---------------- scan A: per-group column partial sums (fully parallel) ----------------
// grid = 2 matrices x (RB/GRP) groups x 4 column-chunks
__global__ void k_scanA(const int* __restrict__ histS, const int* __restrict__ histD,
                        int* __restrict__ psumS, int* __restrict__ psumD) {
    int bid = blockIdx.x;
    int m = bid >> 6;                 // 0 = S, 1 = D
    int g = (bid >> 2) & (RB / GRP - 1);
    int c = bid & 3;
    const int* hist = m ? histD : histS;
    int* psum = m ? psumD : psumS;
    int k = c * 256 + threadIdx.x;
    int s = 0;
#pragma unroll
    for (int r = 0; r < GRP; ++r)
        s += hist[(g * GRP + r) * NBUCK + k];
    psum[g * NBUCK + k] = s;
}

// ---------------- scan B: group-level scan + bucket-base scan ----------------
// block 0: S matrix, block 1: D matrix. Writes base[k] (+ base[NBUCK]) and
// grpbase[g][k] = base[k] + exclusive-sum of groups < g.
__global__ void k_scanB(const int* __restrict__ psumS, int* __restrict__ baseS,
                        int* __restrict__ grpbaseS,
                        const int* __restrict__ psumD, int* __restrict__ baseD,
                        int* __restrict__ grpbaseD) {
    const int* psum = blockIdx.x ? psumD : psumS;
    int* base    = blockIdx.x ? baseD : baseS;
    int* grpbase = blockIdx.x ? grpbaseD : grpbaseS;
    __shared__ int s[NBUCK];
    int k = threadIdx.x;
    int ge[RB / GRP];
    int run = 0;
#pragma unroll
    for (int g = 0; g < RB / GRP; ++g) { ge[g] = run; run += psum[g * NBUCK + k]; }
    s[k] = run;
    __syncthreads();
    for (int off = 1; off < NBUCK; off <<= 1) {
        int t = (k >= off) ? s[k - off] : 0;
        __syncthreads();
        s[k] += t;
        __syncthreads();
    }
    int excl = (k > 0) ? s[k - 1] : 0;
    base[k] = excl;
    if (k == NBUCK - 1) base[NBUCK] = s[NBUCK - 1];
#pragma unroll
    for (int g = 0; g < RB / GRP; ++g)
        grpbase[g * NBUCK + k] = excl + ge[g];
}

// ---------------- coarse partition: LDS cursors per block, no global atomics ----------------
// Cursor init reconstructs this block's exclusive offset from grpbase + rows in-group.
__global__ void k_bucket(const int* __restrict__ src, const int* __restrict__ dst,
                         const int* __restrict__ histS, const int* __restrict__ histD,
                         const int* __restrict__ grpbaseS, const int* __restrict__ grpbaseD,
                         unsigned char* __restrict__ tmpS, int* __restrict__ tmpD,
                         int E, int chunk) {
    __shared__ int curS[NBUCK], curD[NBUCK];
    int tid = threadIdx.x;
    int b = blockIdx.x;
    int g = b / GRP;
    int rs = 0, rd = 0;
    for (int r = g * GRP; r < b; ++r) {
        rs += histS[r * NBUCK + tid];
        rd += histD[r * NBUCK + tid];
    }
    curS[tid] = grpbaseS[g * NBUCK + tid] + rs;
    curD[tid] = grpbaseD[g * NBUCK + tid] + rd;
    __syncthreads();
    int beg = b * chunk;
    int end = min(E, beg + chunk);
    int i = beg + tid * 4;
    for (; i + 3 < end; i += RT * 4) {
        int4 s = *(const int4*)(src + i);
        int4 d = *(const int4*)(dst + i);
        int p;
        p = atomicAdd(&curS[s.x >> LOWB], 1); tmpS[p] = (unsigned char)(s.x & LOWMASK);
        p = atomicAdd(&curS[s.y >> LOWB], 1); tmpS[p] = (unsigned char)(s.y & LOWMASK);
        p = atomicAdd(&curS[s.z >> LOWB], 1); tmpS[p] = (unsigned char)(s.z & LOWMASK);
        p = atomicAdd(&curS[s.w >> LOWB], 1); tmpS[p] = (unsigned char)(s.w & LOWMASK);
        p = atomicAdd(&curD[d.x >> LOWB], 1); tmpD[p] = (s.x << LOWB) | (d.x & LOWMASK);
        p = atomicAdd(&curD[d.y >> LOWB], 1); tmpD[p] = (s.y << LOWB) | (d.y & LOWMASK);
        p = atomicAdd(&curD[d.z >> LOWB], 1); tmpD[p] = (s.z << LOWB) | (d.z & LOWMASK);
        p = atomicAdd(&curD[d.w >> LOWB], 1); tmpD[p] = (s.w << LOWB) | (d.w & LOWMASK);
    }
    if (i < end) {
        for (int j = i; j < end && j < i + 4; ++j) {
            int sv = src[j], dv = dst[j];
            int p = atomicAdd(&curS[sv >> LOWB], 1);
            tmpS[p] = (unsigned char)(sv & LOWMASK);
            p = atomicAdd(&curD[dv >> LOWB], 1);
            tmpD[p] = (sv << LOWB) | (dv & LOWMASK);
        }
    }
}

// ---------------- merged fine pass (one dispatch, two jobs running concurrently) ------
__global__ void k_fine(const int* __restrict__ tmpD, const int* __restrict__ baseD,
                       int* __restrict__ csr_src, int* __restrict__ rowptr,
                       const unsigned char* __restrict__ tmpS, const int* __restrict__ baseS,
                       int* __restrict__ degO, const float* __restrict__ x,
                       __half* __restrict__ bufA, int N, int nbuck) {
    __shared__ int hist[128];
    __shared__ int scanv[128];
    int tid = threadIdx.x;
    if (blockIdx.x < nbuck) {
        int b = blockIdx.x;
        int s0 = baseD[b];
        int s1 = baseD[b + 1];
        if (tid < 128) hist[tid] = 0;
        __syncthreads();
        for (int i = s0 + tid; i < s1; i += 256)
            atomicAdd(&hist[tmpD[i] & LOWMASK], 1);
        __syncthreads();
        int mine = (tid < 128) ? hist[tid] : 0;
        if (tid < 128) scanv[tid] = mine;
        __syncthreads();
        for (int off = 1; off < 128; off <<= 1) {
            int t = (tid < 128 && tid >= off) ? scanv[tid - off] : 0;
            __syncthreads();
            if (tid < 128) scanv[tid] += t;
            __syncthreads();
        }
        if (tid < 128) {
            int excl = scanv[tid] - mine;       // exclusive scan
            int d = (b << LOWB) + tid;
            if (d <= N) rowptr[d] = s0 + excl;  // covers rowptr[N]=E too
            hist[tid] = excl;                   // LDS cursors
        }
        __syncthreads();
        for (int i = s0 + tid; i < s1; i += 256) {
            int p = tmpD[i];
            int pos = atomicAdd(&hist[p & LOWMASK], 1);
            csr_src[s0 + pos] = p >> LOWB;
        }
    } else {
        int b = blockIdx.x - nbuck;
        int s0 = baseS[b];
        int s1 = baseS[b + 1];
        if (tid < 128) hist[tid] = 0;
        __syncthreads();
        for (int i = s0 + tid; i < s1; i += 256)
            atomicAdd(&hist[tmpS[i]], 1);
        __syncthreads();
        if (tid < 128) {
            int d = (b << LOWB) + tid;
            if (d < N) degO[d] = hist[tid];
        }
        // scale x rows for this bucket's 128 nodes: thread = (node, half-row part)
        int node = (b << LOWB) + (tid >> 1);
        if (node < N) {
            float rs = rsqrtf((float)max(hist[tid >> 1], 1));
            int part = tid & 1;                 // feats [part*32, part*32+32)
            const float4* xr = (const float4*)(x + (size_t)node * FDIM) + part * 8;
            float4* orow = (float4*)(bufA + (size_t)node * FDIM) + part * 4;
#pragma unroll
            for (int q = 0; q < 4; ++q) {
                float4 a = xr[2 * q];
                float4 c = xr[2 * q + 1];
                union { __half2 h[4]; float4 f; } u;
                u.h[0] = __floats2half2_rn(a.x * rs, a.y * rs);
                u.h[1] = __floats2half2_rn(a.z * rs, a.w * rs);
                u.h[2] = __floats2half2_rn(c.x * rs, c.y * rs);
                u.h[3] = __floats2half2_rn(c.z * rs, c.w * rs);
                orow[q] = u.f;
            }
        }
    }
}

// ---------------- CSR SpMM: 8 rows per wave, 16B/lane slices, fp32 acc ----------------
__global__ void k_spmm8(const __half* __restrict__ hin, const int* __restrict__ rowptr,
                        const int* __restrict__ csr_src, __half* __restrict__ out, int N) {
    int wid = (blockIdx.x * blockDim.x + threadIdx.x) >> 6;
    int lane = threadIdx.x & 63;
    int g = lane >> 3;
    int sl = lane & 7;
    int row = wid * 8 + g;
    bool rv = row < N;
    int start = rv ? rowptr[row] : 0;
    int end   = rv ? rowptr[row + 1] : 0;
    int deg = end - start;
    int md = deg;
    md = max(md, __shfl_xor(md, 8));
    md = max(md, __shfl_xor(md, 16));
    md = max(md, __shfl_xor(md, 32));
    float acc[8] = {0.f, 0.f, 0.f, 0.f, 0.f, 0.f, 0.f, 0.f};
    for (int it = 0; it < md; it += 8) {
        int a = start + it + sl;
        int ca = (a < end) ? a : ((deg > 0) ? end - 1 : 0);
        int idxv = csr_src[ca];
#pragma unroll
        for (int j = 0; j < 8; ++j) {
            int bidx = __shfl(idxv, (g << 3) + j);
            if (it + j < deg) {
                const float4* gp = (const float4*)(hin + ((size_t)bidx << 6));
                union { float4 f; __half2 h[4]; } u;
                u.f = gp[sl];
                float2 p0 = __half22float2(u.h[0]);
                float2 p1 = __half22float2(u.h[1]);
                float2 p2 = __half22float2(u.h[2]);
                float2 p3 = __half22float2(u.h[3]);
                acc[0] += p0.x; acc[1] += p0.y;
                acc[2] += p1.x; acc[3] += p1.y;
                acc[4] += p2.x; acc[5] += p2.y;
                acc[6] += p3.x; acc[7] += p3.y;
            }
        }
    }
    if (rv) {
        float rs = rsqrtf(fmaxf((float)deg, 1.0f));
        union { float4 f; __half2 h[4]; } o;
        o.h[0] = __floats2half2_rn(acc[0] * rs, acc[1] * rs);
        o.h[1] = __floats2half2_rn(acc[2] * rs, acc[3] * rs);
        o.h[2] = __floats2half2_rn(acc[4] * rs, acc[5] * rs);
        o.h[3] = __floats2half2_rn(acc[6] * rs, acc[7] * rs);
        ((float4*)(out + ((size_t)row << 6)))[sl] = o.f;
    }
}

// ---------------- register GEMM: 1 thread = 1 node; fp16 m in, fp16 h out, fp32 math ------
__global__ void k_gemm_reg(const __half* __restrict__ m, const float* __restrict__ W,
                           const float* __restrict__ b, __half* __restrict__ out, int N) {
    int n = blockIdx.x * blockDim.x + threadIdx.x;
    if (n >= N) return;
    const __half2* mrow = (const __half2*)(m + (size_t)n * FDIM);
    float acc[FDIM];
#pragma unroll
    for (int j = 0; j < FDIM; ++j) acc[j] = b[j];        // b[j] wave-uniform -> s_load
    for (int k0 = 0; k0 < FDIM; k0 += 8) {
        float2 f0 = __half22float2(mrow[(k0 >> 1) + 0]);
        float2 f1 = __half22float2(mrow[(k0 >> 1) + 1]);
        float2 f2 = __half22float2(mrow[(k0 >> 1) + 2]);
        float2 f3 = __half22float2(mrow[(k0 >> 1) + 3]);
        float mreg[8] = {f0.x, f0.y, f1.x, f1.y, f2.x, f2.y, f3.x, f3.y};
#pragma unroll
        for (int k1 = 0; k1 < 8; ++k1) {
            const float* Wrow = W + (k0 + k1) * FDIM;    // wave-uniform row -> s_load
#pragma unroll
            for (int j = 0; j < FDIM; ++j)
                acc[j] = fmaf(mreg[k1], Wrow[j], acc[j]);
        }
    }
    float4* orow = (float4*)(out + (size_t)n * FDIM);
#pragma unroll
    for (int j = 0; j < FDIM; j += 8) {
        union { __half2 h[4]; float4 f; } u;
        u.h[0] = __floats2half2_rn(acc[j + 0], acc[j + 1]);
        u.h[1] = __floats2half2_rn(acc[j + 2], acc[j + 3]);
        u.h[2] = __floats2half2_rn(acc[j + 4], acc[j + 5]);
        u.h[3] = __floats2half2_rn(acc[j + 6], acc[j + 7]);
        orow[j >> 3] = u.f;
    }
}

// ---------------- BN stats + (last block) finalize mu/coef ----------------
__global__ void k_stats_fin(const __half* __restrict__ h, float* __restrict__ ssum,
                            float* __restrict__ ssq, const float* __restrict__ g,
                            float* __restrict__ mu, float* __restrict__ coef,
                            int* __restrict__ cnt, int N) {
    __shared__ float red[256];
    __shared__ int last;
    int tid = threadIdx.x;
    int j  = tid & 63;
    int nl = tid >> 6;
    float ls = 0.f, lq = 0.f;
    int stride = gridDim.x * 4;
    for (int n = blockIdx.x * 4 + nl; n < N; n += stride) {
        float v = __half2float(h[(size_t)n * FDIM + j]);
        ls += v;
        lq += v * v;
    }
    red[tid] = ls;
    __syncthreads();
    if (nl == 0) atomicAdd(&ssum[j], red[j] + red[64 + j] + red[128 + j] + red[192 + j]);
    __syncthreads();
    red[tid] = lq;
    __syncthreads();
    if (nl == 0) atomicAdd(&ssq[j], red[j] + red[64 + j] + red[128 + j] + red[192 + j]);
    __threadfence();
    __syncthreads();
    if (tid == 0) last = (atomicAdd(cnt, 1) == (int)gridDim.x - 1);
    __syncthreads();
    if (last && tid < 64) {
        float s = __hip_atomic_load(&ssum[tid], __ATOMIC_RELAXED, __HIP_MEMORY_SCOPE_AGENT);
        float q = __hip_atomic_load(&ssq[tid],  __ATOMIC_RELAXED, __HIP_MEMORY_SCOPE_AGENT);
        float m = s / (float)N;
        float v = q / (float)N - m * m;
        mu[tid] = m;
        coef[tid] = rsqrtf(v + EPS) * g[tid];
    }
}

// ---------------- out = half(relu((h-mu)*coef+be) * rsqrt(max(degO,1))) ----------------
__global__ void k_bnrelu_scale(const float2* __restrict__ h, const float* __restrict__ mu,
                               const float* __restrict__ coef, const float* __restrict__ be,
                               const int* __restrict__ degO, float2* __restrict__ out, int n4) {
    int i = blockIdx.x * blockDim.x + threadIdx.x;
    if (i < n4) {
        int n = i >> 4;
        int j4 = (i & 15) << 2;
        float rs = rsqrtf((float)max(degO[n], 1));
        union { __half2 hh[2]; float2 f; } u;
        u.f = h[i];
        float2 v0 = __half22float2(u.hh[0]);
        float2 v1 = __half22float2(u.hh[1]);
        float r0 = fmaxf((v0.x - mu[j4 + 0]) * coef[j4 + 0] + be[j4 + 0], 0.f) * rs;
        float r1 = fmaxf((v0.y - mu[j4 + 1]) * coef[j4 + 1] + be[j4 + 1], 0.f) * rs;
        float r2 = fmaxf((v1.x - mu[j4 + 2]) * coef[j4 + 2] + be[j4 + 2], 0.f) * rs;
        float r3 = fmaxf((v1.y - mu[j4 + 3]) * coef[j4 + 3] + be[j4 + 3], 0.f) * rs;
        union { __half2 hh[2]; float2 f; } o;
        o.hh[0] = __floats2half2_rn(r0, r1);
        o.hh[1] = __floats2half2_rn(r2, r3);
        out[i] = o.f;
    }
}

// ---------------- relu(bn(h)) channel-sum + (last block) classifier ----------------
__global__ void k_bnmean_fin(const __half* __restrict__ h, const float* __restrict__ mu,
                             const float* __restrict__ coef, const float* __restrict__ be,
                             float* __restrict__ hsum, const float* __restrict__ Wc,
                             const float* __restrict__ bc, float* __restrict__ out,
                             int* __restrict__ cnt, int N) {
    __shared__ float red[256];
    __shared__ int last;
    int tid = threadIdx.x;
    int j  = tid & 63;
    int nl = tid >> 6;
    float muj = mu[j], cj = coef[j], bj = be[j];
    float ls = 0.f;
    int stride = gridDim.x * 4;
    for (int n = blockIdx.x * 4 + nl; n < N; n += stride) {
        float v = fmaxf((__half2float(h[(size_t)n * FDIM + j]) - muj) * cj + bj, 0.f);
        ls += v;
    }
    red[tid] = ls;
    __syncthreads();
    if (nl == 0) atomicAdd(&hsum[j], red[j] + red[64 + j] + red[128 + j] + red[192 + j]);
    __threadfence();
    __syncthreads();
    if (tid == 0) last = (atomicAdd(cnt, 1) == (int)gridDim.x - 1);
    __syncthreads();
    if (last) {
        if (tid < 64) {
            float hg = __hip_atomic_load(&hsum[tid], __ATOMIC_RELAXED,
                                         __HIP_MEMORY_SCOPE_AGENT) / (float)N;
            red[tid]      = hg * Wc[tid * 2 + 0];
            red[64 + tid] = hg * Wc[tid * 2 + 1];
        }
        __syncthreads();
        if (tid == 0) {
            float a = 0.f, b = 0.f;
            for (int k = 0; k < 64; ++k) { a += red[k]; b += red[64 + k]; }
            out[0] = a + bc[0];
            out[1] = b + bc[1];
        }
    }
}

extern "C" void kernel_launch(void* const* d_in, const int* in_sizes, int n_in,
                              void* d_out, int out_size, void* d_ws, size_t ws_size,
                              hipStream_t stream) {
    const float* x   = (const float*)d_in[0];
    const int*   src = (const int*)d_in[1];
    const int*   dst = (const int*)d_in[2];
    const float* W1  = (const float*)d_in[3];
    const float* b1  = (const float*)d_in[4];
    const float* g1  = (const float*)d_in[5];
    const float* be1 = (const float*)d_in[6];
    const float* W2  = (const float*)d_in[7];
    const float* b2  = (const float*)d_in[8];
    const float* g2  = (const float*)d_in[9];
    const float* be2 = (const float*)d_in[10];
    const float* Wc  = (const float*)d_in[11];
    const float* bc  = (const float*)d_in[12];
    float* out = (float*)d_out;

    const int N = in_sizes[0] / FDIM;   // 100000
    const int E = in_sizes[1];          // 1600000

    // ---- workspace layout ----
    char* w = (char*)d_ws;
    __half* bufA   = (__half*)w;                                  // N*64 halfs (12.8 MB)
    __half* bufB   = bufA + (size_t)N * FDIM;                     // N*64 halfs
    int*   csr_src = (int*)(bufB + (size_t)N * FDIM);             // E int
    int*   degO    = csr_src + E;                                 // N int
    int*   rowptr  = degO + N;                                    // N+2 int
    int*   histS   = rowptr + N + 2;                              // RB*NBUCK int
    int*   histD   = histS + RB * NBUCK;                          // RB*NBUCK int
    int*   baseS   = histD + RB * NBUCK;                          // NBUCK+1
    int*   baseD   = baseS + NBUCK + 1;                           // NBUCK+1
    int*   psumS   = baseD + NBUCK + 1;                           // (RB/GRP)*NBUCK
    int*   psumD   = psumS + (RB / GRP) * NBUCK;                  // (RB/GRP)*NBUCK
    int*   grpbaseS= psumD + (RB / GRP) * NBUCK;                  // (RB/GRP)*NBUCK
    int*   grpbaseD= grpbaseS + (RB / GRP) * NBUCK;               // (RB/GRP)*NBUCK
    float* stats   = (float*)(grpbaseD + (RB / GRP) * NBUCK);     // 1024 f } memset
    unsigned char* tmpS = (unsigned char*)(stats + 1024);         // E bytes (dedicated)
    int*           tmpD = (int*)bufB;                             // E int, aliases bufB (dead)

    float* sum1  = stats + 0;
    float* sq1   = stats + 64;
    float* mu1   = stats + 128;
    float* coef1 = stats + 192;
    float* sum2  = stats + 256;
    float* sq2   = stats + 320;
    float* mu2   = stats + 384;
    float* coef2 = stats + 448;
    float* hsum  = stats + 512;
    int*   cnt1  = (int*)(stats + 576);
    int*   cnt2  = (int*)(stats + 577);
    int*   cnt3  = (int*)(stats + 578);

    const int n4 = N * (FDIM / 4);
    const int spmm8_blocks = ((N + 7) / 8 + 3) / 4;       // 8 rows/wave, 4 waves/block
    const int nbuck_active = (N + LOWMASK) >> LOWB;       // 782 for N=100000
    const int chunk = ((E + RB - 1) / RB + 3) & ~3;       // per-block edges, mult of 4

    hipMemsetAsync(stats, 0, 1024 * 4, stream);

    k_hist<<<RB, RT, 0, stream>>>(src, dst, histS, histD, E, chunk);
    k_scanA<<<2 * (RB / GRP) * 4, 256, 0, stream>>>(histS, histD, psumS, psumD);
    k_scanB<<<2, NBUCK, 0, stream>>>(psumS, baseS, grpbaseS, psumD, baseD, grpbaseD);
    k_bucket<<<RB, RT, 0, stream>>>(src, dst, histS, histD, grpbaseS, grpbaseD,
                                    tmpS, tmpD, E, chunk);
    k_fine<<<2 * nbuck_active, 256, 0, stream>>>(tmpD, baseD, csr_src, rowptr,
                                                 tmpS, baseS, degO, x, bufA, N, nbuck_active);

    k_spmm8<<<spmm8_blocks, 256, 0, stream>>>(bufA, rowptr, csr_src, bufB, N);
    k_gemm_reg<<<(N + 63) / 64, 64, 0, stream>>>(bufB, W1, b1, bufA, N);
    k_stats_fin<<<512, 256, 0, stream>>>(bufA, sum1, sq1, g1, mu1, coef1, cnt1, N);
    k_bnrelu_scale<<<(n4 + 255) / 256, 256, 0, stream>>>((const float2*)bufA, mu1, coef1, be1,
                                                         degO, (float2*)bufB, n4);
    k_spmm8<<<spmm8_blocks, 256, 0, stream>>>(bufB, rowptr, csr_src, bufA, N);
    k_gemm_reg<<<(N + 63) / 64, 64, 0, stream>>>(bufA, W2, b2, bufB, N);
    k_stats_fin<<<512, 256, 0, stream>>>(bufB, sum2, sq2, g2, mu2, coef2, cnt2, N);
    k_bnmean_fin<<<512, 256, 0, stream>>>(bufB, mu2, coef2, be2, hsum, Wc, bc, out, cnt3, N);
}

// Round 11
// 399.571 us; speedup vs baseline: 1.1440x; 1.0233x over previous
//
#include <hip/hip_runtime.h>
#include <hip/hip_fp16.h>

#define FDIM 64
#define EPS 1e-5f
#define NBUCK 1024     // coarse buckets = high bits of 17-bit id
#define LOWB 7
#define LOWMASK 127
#define RB 256         // radix blocks
#define RT 1024        // radix threads per block
#define GRP 16         // rows per scan group (RB/GRP groups)

// ---------------- per-block coarse histograms of src>>7 and dst>>7 ----------------
__global__ void k_hist(const int* __restrict__ src, const int* __restrict__ dst,
                       int* __restrict__ histS, int* __restrict__ histD, int E, int chunk) {
    __shared__ int hs[NBUCK], hd[NBUCK];
    int tid = threadIdx.x;            // RT == NBUCK == 1024
    hs[tid] = 0; hd[tid] = 0;
    __syncthreads();
    int b = blockIdx.x;
    int beg = b * chunk;
    int end = min(E, beg + chunk);
    int i = beg + tid * 4;
    for (; i + 3 < end; i += RT * 4) {
        int4 s = *(const int4*)(src + i);
        int4 d = *(const int4*)(dst + i);
        atomicAdd(&hs[s.x >> LOWB], 1); atomicAdd(&hd[d.x >> LOWB], 1);
        atomicAdd(&hs[s.y >> LOWB], 1); atomicAdd(&hd[d.y >> LOWB], 1);
        atomicAdd(&hs[s.z >> LOWB], 1); atomicAdd(&hd[d.z >> LOWB], 1);
        atomicAdd(&hs[s.w >> LOWB], 1); atomicAdd(&hd[d.w >> LOWB], 1);
    }
    if (i < end) {
        for (int j = i; j < end && j < i + 4; ++j) {
            atomicAdd(&hs[src[j] >> LOWB], 1);
            atomicAdd(&hd[dst[j] >> LOWB], 1);
        }
    }
    __syncthreads();
    histS[b * NBUCK + tid] = hs[tid];
    histD[b * NBUCK + tid] = hd[tid];
}

// ---------------- scan A: per-group column partial sums (fully parallel) ----------------
__global__ void k_scanA(const int* __restrict__ histS, const int* __restrict__ histD,
                        int* __restrict__ psumS, int* __restrict__ psumD) {
    int bid = blockIdx.x;
    int m = bid >> 6;                 // 0 = S, 1 = D
    int g = (bid >> 2) & (RB / GRP - 1);
    int c = bid & 3;
    const int* hist = m ? histD : histS;
    int* psum = m ? psumD : psumS;
    int k = c * 256 + threadIdx.x;
    int s = 0;
#pragma unroll
    for (int r = 0; r < GRP; ++r)
        s += hist[(g * GRP + r) * NBUCK + k];
    psum[g * NBUCK + k] = s;
}

// ---------------- scan B: group-level scan + bucket-base scan ----------------
__global__ void k_scanB(const int* __restrict__ psumS, int* __restrict__ baseS,
                        int* __restrict__ grpbaseS,
                        const int* __restrict__ psumD, int* __restrict__ baseD,
                        int* __restrict__ grpbaseD) {
    const int* psum = blockIdx.x ? psumD : psumS;
    int* base    = blockIdx.x ? baseD : baseS;
    int* grpbase = blockIdx.x ? grpbaseD : grpbaseS;
    __shared__ int s[NBUCK];
    int k = threadIdx.x;
    int ge[RB / GRP];
    int run = 0;
#pragma unroll
    for (int g = 0; g < RB / GRP; ++g) { ge[g] = run; run += psum[g * NBUCK + k]; }
    s[k] = run;
    __syncthreads();
    for (int off = 1; off < NBUCK; off <<= 1) {
        int t = (k >= off) ? s[k - off] : 0;
        __syncthreads();
        s[k] += t;
        __syncthreads();
    }
    int excl = (k > 0) ? s[k - 1] : 0;
    base[k] = excl;
    if (k == NBUCK - 1) base[NBUCK] = s[NBUCK - 1];
#pragma unroll
    for (int g = 0; g < RB / GRP; ++g)
        grpbase[g * NBUCK + k] = excl + ge[g];
}

// ---------------- coarse partition: LDS cursors per block, no global atomics ----------------
__global__ void k_bucket(const int* __restrict__ src, const int* __restrict__ dst,
                         const int* __restrict__ histS, const int* __restrict__ histD,
                         const int* __restrict__ grpbaseS, const int* __restrict__ grpbaseD,
                         unsigned char* __restrict__ tmpS, int* __restrict__ tmpD,
                         int E, int chunk) {
    __shared__ int curS[NBUCK], curD[NBUCK];
    int tid = threadIdx.x;
    int b = blockIdx.x;
    int g = b / GRP;
    int rs = 0, rd = 0;
    for (int r = g * GRP; r < b; ++r) {
        rs += histS[r * NBUCK + tid];
        rd += histD[r * NBUCK + tid];
    }
    curS[tid] = grpbaseS[g * NBUCK + tid] + rs;
    curD[tid] = grpbaseD[g * NBUCK + tid] + rd;
    __syncthreads();
    int beg = b * chunk;
    int end = min(E, beg + chunk);
    int i = beg + tid * 4;
    for (; i + 3 < end; i += RT * 4) {
        int4 s = *(const int4*)(src + i);
        int4 d = *(const int4*)(dst + i);
        int p;
        p = atomicAdd(&curS[s.x >> LOWB], 1); tmpS[p] = (unsigned char)(s.x & LOWMASK);
        p = atomicAdd(&curS[s.y >> LOWB], 1); tmpS[p] = (unsigned char)(s.y & LOWMASK);
        p = atomicAdd(&curS[s.z >> LOWB], 1); tmpS[p] = (unsigned char)(s.z & LOWMASK);
        p = atomicAdd(&curS[s.w >> LOWB], 1); tmpS[p] = (unsigned char)(s.w & LOWMASK);
        p = atomicAdd(&curD[d.x >> LOWB], 1); tmpD[p] = (s.x << LOWB) | (d.x & LOWMASK);
        p = atomicAdd(&curD[d.y >> LOWB], 1); tmpD[p] = (s.y << LOWB) | (d.y & LOWMASK);
        p = atomicAdd(&curD[d.z >> LOWB], 1); tmpD[p] = (s.z << LOWB) | (d.z & LOWMASK);
        p = atomicAdd(&curD[d.w >> LOWB], 1); tmpD[p] = (s.w << LOWB) | (d.w & LOWMASK);
    }
    if (i < end) {
        for (int j = i; j < end && j < i + 4; ++j) {
            int sv = src[j], dv = dst[j];
            int p = atomicAdd(&curS[sv >> LOWB], 1);
            tmpS[p] = (unsigned char)(sv & LOWMASK);
            p = atomicAdd(&curD[dv >> LOWB], 1);
            tmpD[p] = (sv << LOWB) | (dv & LOWMASK);
        }
    }
}

// ---------------- merged fine pass (one dispatch, two jobs running concurrently) ------
__global__ void k_fine(const int* __restrict__ tmpD, const int* __restrict__ baseD,
                       int* __restrict__ csr_src, int* __restrict__ rowptr,
                       const unsigned char* __restrict__ tmpS, const int* __restrict__ baseS,
                       int* __restrict__ degO, const float* __restrict__ x,
                       __half* __restrict__ bufA, int N, int nbuck) {
    __shared__ int hist[128];
    __shared__ int scanv[128];
    int tid = threadIdx.x;
    if (blockIdx.x < nbuck) {
        int b = blockIdx.x;
        int s0 = baseD[b];
        int s1 = baseD[b + 1];
        if (tid < 128) hist[tid] = 0;
        __syncthreads();
        for (int i = s0 + tid; i < s1; i += 256)
            atomicAdd(&hist[tmpD[i] & LOWMASK], 1);
        __syncthreads();
        int mine = (tid < 128) ? hist[tid] : 0;
        if (tid < 128) scanv[tid] = mine;
        __syncthreads();
        for (int off = 1; off < 128; off <<= 1) {
            int t = (tid < 128 && tid >= off) ? scanv[tid - off] : 0;
            __syncthreads();
            if (tid < 128) scanv[tid] += t;
            __syncthreads();
        }
        if (tid < 128) {
            int excl = scanv[tid] - mine;       // exclusive scan
            int d = (b << LOWB) + tid;
            if (d <= N) rowptr[d] = s0 + excl;  // covers rowptr[N]=E too
            hist[tid] = excl;                   // LDS cursors
        }
        __syncthreads();
        for (int i = s0 + tid; i < s1; i += 256) {
            int p = tmpD[i];
            int pos = atomicAdd(&hist[p & LOWMASK], 1);
            csr_src[s0 + pos] = p >> LOWB;
        }
    } else {
        int b = blockIdx.x - nbuck;
        int s0 = baseS[b];
        int s1 = baseS[b + 1];
        if (tid < 128) hist[tid] = 0;
        __syncthreads();
        for (int i = s0 + tid; i < s1; i += 256)
            atomicAdd(&hist[tmpS[i]], 1);
        __syncthreads();
        if (tid < 128) {
            int d = (b << LOWB) + tid;
            if (d < N) degO[d] = hist[tid];
        }
        // scale x rows for this bucket's 128 nodes: thread = (node, half-row part)
        int node = (b << LOWB) + (tid >> 1);
        if (node < N) {
            float rs = rsqrtf((float)max(hist[tid >> 1], 1));
            int part = tid & 1;                 // feats [part*32, part*32+32)
            const float4* xr = (const float4*)(x + (size_t)node * FDIM) + part * 8;
            float4* orow = (float4*)(bufA + (size_t)node * FDIM) + part * 4;
#pragma unroll
            for (int q = 0; q < 4; ++q) {
                float4 a = xr[2 * q];
                float4 c = xr[2 * q + 1];
                union { __half2 h[4]; float4 f; } u;
                u.h[0] = __floats2half2_rn(a.x * rs, a.y * rs);
                u.h[1] = __floats2half2_rn(a.z * rs, a.w * rs);
                u.h[2] = __floats2half2_rn(c.x * rs, c.y * rs);
                u.h[3] = __floats2half2_rn(c.z * rs, c.w * rs);
                orow[q] = u.f;
            }
        }
    }
}

// ---------------- CSR SpMM: 8 rows per wave, 16B/lane slices, fp32 acc ----------------
__global__ void k_spmm8(const __half* __restrict__ hin, const int* __restrict__ rowptr,
                        const int* __restrict__ csr_src, __half* __restrict__ out, int N) {
    int wid = (blockIdx.x * blockDim.x + threadIdx.x) >> 6;
    int lane = threadIdx.x & 63;
    int g = lane >> 3;
    int sl = lane & 7;
    int row = wid * 8 + g;
    bool rv = row < N;
    int start = rv ? rowptr[row] : 0;
    int end   = rv ? rowptr[row + 1] : 0;
    int deg = end - start;
    int md = deg;
    md = max(md, __shfl_xor(md, 8));
    md = max(md, __shfl_xor(md, 16));
    md = max(md, __shfl_xor(md, 32));
    float acc[8] = {0.f, 0.f, 0.f, 0.f, 0.f, 0.f, 0.f, 0.f};
    for (int it = 0; it < md; it += 8) {
        int a = start + it + sl;
        int ca = (a < end) ? a : ((deg > 0) ? end - 1 : 0);
        int idxv = csr_src[ca];
#pragma unroll
        for (int j = 0; j < 8; ++j) {
            int bidx = __shfl(idxv, (g << 3) + j);
            if (it + j < deg) {
                const float4* gp = (const float4*)(hin + ((size_t)bidx << 6));
                union { float4 f; __half2 h[4]; } u;
                u.f = gp[sl];
                float2 p0 = __half22float2(u.h[0]);
                float2 p1 = __half22float2(u.h[1]);
                float2 p2 = __half22float2(u.h[2]);
                float2 p3 = __half22float2(u.h[3]);
                acc[0] += p0.x; acc[1] += p0.y;
                acc[2] += p1.x; acc[3] += p1.y;
                acc[4] += p2.x; acc[5] += p2.y;
                acc[6] += p3.x; acc[7] += p3.y;
            }
        }
    }
    if (rv) {
        float rs = rsqrtf(fmaxf((float)deg, 1.0f));
        union { float4 f; __half2 h[4]; } o;
        o.h[0] = __floats2half2_rn(acc[0] * rs, acc[1] * rs);
        o.h[1] = __floats2half2_rn(acc[2] * rs, acc[3] * rs);
        o.h[2] = __floats2half2_rn(acc[4] * rs, acc[5] * rs);
        o.h[3] = __floats2half2_rn(acc[6] * rs, acc[7] * rs);
        ((float4*)(out + ((size_t)row << 6)))[sl] = o.f;
    }
}

// ---------------- register GEMM: 1 thread = 1 node; fp16 m in, fp16 h out, fp32 math ------
__global__ void k_gemm_reg(const __half* __restrict__ m, const float* __restrict__ W,
                           const float* __restrict__ b, __half* __restrict__ out, int N) {
    int n = blockIdx.x * blockDim.x + threadIdx.x;
    if (n >= N) return;
    const __half2* mrow = (const __half2*)(m + (size_t)n * FDIM);
    float acc[FDIM];
#pragma unroll
    for (int j = 0; j < FDIM; ++j) acc[j] = b[j];        // b[j] wave-uniform -> s_load
    for (int k0 = 0; k0 < FDIM; k0 += 8) {
        float2 f0 = __half22float2(mrow[(k0 >> 1) + 0]);
        float2 f1 = __half22float2(mrow[(k0 >> 1) + 1]);
        float2 f2 = __half22float2(mrow[(k0 >> 1) + 2]);
        float2 f3 = __half22float2(mrow[(k0 >> 1) + 3]);
        float mreg[8] = {f0.x, f0.y, f1.x, f1.y, f2.x, f2.y, f3.x, f3.y};
#pragma unroll
        for (int k1 = 0; k1 < 8; ++k1) {
            const float* Wrow = W + (k0 + k1) * FDIM;    // wave-uniform row -> s_load
#pragma unroll
            for (int j = 0; j < FDIM; ++j)
                acc[j] = fmaf(mreg[k1], Wrow[j], acc[j]);
        }
    }
    float4* orow = (float4*)(out + (size_t)n * FDIM);
#pragma unroll
    for (int j = 0; j < FDIM; j += 8) {
        union { __half2 h[4]; float4 f; } u;
        u.h[0] = __floats2half2_rn(acc[j + 0], acc[j + 1]);
        u.h[1] = __floats2half2_rn(acc[j + 2], acc[j + 3]);
        u.h[2] = __floats2half2_rn(acc[j + 4], acc[j + 5]);
        u.h[3] = __floats2half2_rn(acc[j + 6], acc[j + 7]);
        orow[j >> 3] = u.f;
    }
}

// ---------------- BN stats (vectorized, shfl-reduced) + last-block finalize ----------------
// thread = (node lane nl = tid>>3, 8-channel slice sl = tid&7); float4 loads.
// NO __threadfence: block's device atomics complete before the acq_rel counter bump
// (syncthreads drains vmcnt), so the last block can safely read the totals.
__global__ void k_stats_fin(const __half* __restrict__ h, float* __restrict__ ssum,
                            float* __restrict__ ssq, const float* __restrict__ g,
                            float* __restrict__ mu, float* __restrict__ coef,
                            int* __restrict__ cnt, int N) {
    __shared__ float red[4][128];
    __shared__ int lastv;
    int tid = threadIdx.x;
    int sl = tid & 7;
    int nl = tid >> 3;
    float s[8] = {0.f,0.f,0.f,0.f,0.f,0.f,0.f,0.f};
    float q[8] = {0.f,0.f,0.f,0.f,0.f,0.f,0.f,0.f};
    int stride = gridDim.x * 32;
    for (int n = blockIdx.x * 32 + nl; n < N; n += stride) {
        union { float4 f; __half2 hh[4]; } u;
        u.f = ((const float4*)(h + ((size_t)n << 6)))[sl];
#pragma unroll
        for (int p = 0; p < 4; ++p) {
            float2 v = __half22float2(u.hh[p]);
            s[2*p]   += v.x; q[2*p]   += v.x * v.x;
            s[2*p+1] += v.y; q[2*p+1] += v.y * v.y;
        }
    }
#pragma unroll
    for (int off = 8; off < 64; off <<= 1) {
#pragma unroll
        for (int p = 0; p < 8; ++p) {
            s[p] += __shfl_xor(s[p], off);
            q[p] += __shfl_xor(q[p], off);
        }
    }
    int wv = tid >> 6, lane = tid & 63;
    if (lane < 8) {
#pragma unroll
        for (int p = 0; p < 8; ++p) {
            red[wv][lane * 8 + p] = s[p];
            red[wv][64 + lane * 8 + p] = q[p];
        }
    }
    __syncthreads();
    if (tid < 128) {
        float v = red[0][tid] + red[1][tid] + red[2][tid] + red[3][tid];
        if (tid < 64) atomicAdd(&ssum[tid], v);
        else          atomicAdd(&ssq[tid - 64], v);
    }
    __syncthreads();
    if (tid == 0)
        lastv = (__hip_atomic_fetch_add(cnt, 1, __ATOMIC_ACQ_REL,
                                        __HIP_MEMORY_SCOPE_AGENT) == (int)gridDim.x - 1);
    __syncthreads();
    if (lastv && tid < 64) {
        float sv = __hip_atomic_load(&ssum[tid], __ATOMIC_RELAXED, __HIP_MEMORY_SCOPE_AGENT);
        float qv = __hip_atomic_load(&ssq[tid],  __ATOMIC_RELAXED, __HIP_MEMORY_SCOPE_AGENT);
        float m = sv / (float)N;
        float var = qv / (float)N - m * m;
        mu[tid] = m;
        coef[tid] = rsqrtf(var + EPS) * g[tid];
    }
}

// ---------------- out = half(relu((h-mu)*coef+be) * rsqrt(max(degO,1))) ----------------
__global__ void k_bnrelu_scale(const float2* __restrict__ h, const float* __restrict__ mu,
                               const float* __restrict__ coef, const float* __restrict__ be,
                               const int* __restrict__ degO, float2* __restrict__ out, int n4) {
    int i = blockIdx.x * blockDim.x + threadIdx.x;
    if (i < n4) {
        int n = i >> 4;
        int j4 = (i & 15) << 2;
        float rs = rsqrtf((float)max(degO[n], 1));
        union { __half2 hh[2]; float2 f; } u;
        u.f = h[i];
        float2 v0 = __half22float2(u.hh[0]);
        float2 v1 = __half22float2(u.hh[1]);
        float r0 = fmaxf((v0.x - mu[j4 + 0]) * coef[j4 + 0] + be[j4 + 0], 0.f) * rs;
        float r1 = fmaxf((v0.y - mu[j4 + 1]) * coef[j4 + 1] + be[j4 + 1], 0.f) * rs;
        float r2 = fmaxf((v1.x - mu[j4 + 2]) * coef[j4 + 2] + be[j4 + 2], 0.f) * rs;
        float r3 = fmaxf((v1.y - mu[j4 + 3]) * coef[j4 + 3] + be[j4 + 3], 0.f) * rs;
        union { __half2 hh[2]; float2 f; } o;
        o.hh[0] = __floats2half2_rn(r0, r1);
        o.hh[1] = __floats2half2_rn(r2, r3);
        out[i] = o.f;
    }
}

// ---------------- relu(bn(h)) channel-sum (vectorized) + last-block classifier --------
__global__ void k_bnmean_fin(const __half* __restrict__ h, const float* __restrict__ mu,
                             const float* __restrict__ coef, const float* __restrict__ be,
                             float* __restrict__ hsum, const float* __restrict__ Wc,
                             const float* __restrict__ bc, float* __restrict__ out,
                             int* __restrict__ cnt, int N) {
    __shared__ float red[4][64];
    __shared__ float cls[128];
    __shared__ int lastv;
    int tid = threadIdx.x;
    int sl = tid & 7;
    int nl = tid >> 3;
    int j8 = sl * 8;
    float m_[8], c_[8], b_[8];
#pragma unroll
    for (int p = 0; p < 8; ++p) { m_[p] = mu[j8 + p]; c_[p] = coef[j8 + p]; b_[p] = be[j8 + p]; }
    float s[8] = {0.f,0.f,0.f,0.f,0.f,0.f,0.f,0.f};
    int stride = gridDim.x * 32;
    for (int n = blockIdx.x * 32 + nl; n < N; n += stride) {
        union { float4 f; __half2 hh[4]; } u;
        u.f = ((const float4*)(h + ((size_t)n << 6)))[sl];
#pragma unroll
        for (int p = 0; p < 4; ++p) {
            float2 v = __half22float2(u.hh[p]);
            s[2*p]   += fmaxf((v.x - m_[2*p])   * c_[2*p]   + b_[2*p],   0.f);
            s[2*p+1] += fmaxf((v.y - m_[2*p+1]) * c_[2*p+1] + b_[2*p+1], 0.f);
        }
    }
#pragma unroll
    for (int off = 8; off < 64; off <<= 1) {
#pragma unroll
        for (int p = 0; p < 8; ++p) s[p] += __shfl_xor(s[p], off);
    }
    int wv = tid >> 6, lane = tid & 63;
    if (lane < 8) {
#pragma unroll
        for (int p = 0; p < 8; ++p) red[wv][lane * 8 + p] = s[p];
    }
    __syncthreads();
    if (tid < 64)
        atomicAdd(&hsum[tid], red[0][tid] + red[1][tid] + red[2][tid] + red[3][tid]);
    __syncthreads();
    if (tid == 0)
        lastv = (__hip_atomic_fetch_add(cnt, 1, __ATOMIC_ACQ_REL,
                                        __HIP_MEMORY_SCOPE_AGENT) == (int)gridDim.x - 1);
    __syncthreads();
    if (lastv) {
        if (tid < 64) {
            float hg = __hip_atomic_load(&hsum[tid], __ATOMIC_RELAXED,
                                         __HIP_MEMORY_SCOPE_AGENT) / (float)N;
            cls[tid]      = hg * Wc[tid * 2 + 0];
            cls[64 + tid] = hg * Wc[tid * 2 + 1];
        }
        __syncthreads();
        if (tid == 0) {
            float a = 0.f, bv = 0.f;
            for (int k = 0; k < 64; ++k) { a += cls[k]; bv += cls[64 + k]; }
            out[0] = a + bc[0];
            out[1] = bv + bc[1];
        }
    }
}

extern "C" void kernel_launch(void* const* d_in, const int* in_sizes, int n_in,
                              void* d_out, int out_size, void* d_ws, size_t ws_size,
                              hipStream_t stream) {
    const float* x   = (const float*)d_in[0];
    const int*   src = (const int*)d_in[1];
    const int*   dst = (const int*)d_in[2];
    const float* W1  = (const float*)d_in[3];
    const float* b1  = (const float*)d_in[4];
    const float* g1  = (const float*)d_in[5];
    const float* be1 = (const float*)d_in[6];
    const float* W2  = (const float*)d_in[7];
    const float* b2  = (const float*)d_in[8];
    const float* g2  = (const float*)d_in[9];
    const float* be2 = (const float*)d_in[10];
    const float* Wc  = (const float*)d_in[11];
    const float* bc  = (const float*)d_in[12];
    float* out = (float*)d_out;

    const int N = in_sizes[0] / FDIM;   // 100000
    const int E = in_sizes[1];          // 1600000

    // ---- workspace layout ----
    char* w = (char*)d_ws;
    __half* bufA   = (__half*)w;                                  // N*64 halfs (12.8 MB)
    __half* bufB   = bufA + (size_t)N * FDIM;                     // N*64 halfs
    int*   csr_src = (int*)(bufB + (size_t)N * FDIM);             // E int
    int*   degO    = csr_src + E;                                 // N int
    int*   rowptr  = degO + N;                                    // N+2 int
    int*   histS   = rowptr + N + 2;                              // RB*NBUCK int
    int*   histD   = histS + RB * NBUCK;                          // RB*NBUCK int
    int*   baseS   = histD + RB * NBUCK;                          // NBUCK+1
    int*   baseD   = baseS + NBUCK + 1;                           // NBUCK+1
    int*   psumS   = baseD + NBUCK + 1;                           // (RB/GRP)*NBUCK
    int*   psumD   = psumS + (RB / GRP) * NBUCK;                  // (RB/GRP)*NBUCK
    int*   grpbaseS= psumD + (RB / GRP) * NBUCK;                  // (RB/GRP)*NBUCK
    int*   grpbaseD= grpbaseS + (RB / GRP) * NBUCK;               // (RB/GRP)*NBUCK
    float* stats   = (float*)(grpbaseD + (RB / GRP) * NBUCK);     // 1024 f } memset
    unsigned char* tmpS = (unsigned char*)(stats + 1024);         // E bytes (dedicated)
    int*           tmpD = (int*)bufB;                             // E int, aliases bufB (dead)

    float* sum1  = stats + 0;
    float* sq1   = stats + 64;
    float* mu1   = stats + 128;
    float* coef1 = stats + 192;
    float* sum2  = stats + 256;
    float* sq2   = stats + 320;
    float* mu2   = stats + 384;
    float* coef2 = stats + 448;
    float* hsum  = stats + 512;
    int*   cnt1  = (int*)(stats + 576);
    int*   cnt2  = (int*)(stats + 577);
    int*   cnt3  = (int*)(stats + 578);

    const int n4 = N * (FDIM / 4);
    const int spmm8_blocks = ((N + 7) / 8 + 3) / 4;       // 8 rows/wave, 4 waves/block
    const int nbuck_active = (N + LOWMASK) >> LOWB;       // 782 for N=100000
    const int chunk = ((E + RB - 1) / RB + 3) & ~3;       // per-block edges, mult of 4

    hipMemsetAsync(stats, 0, 1024 * 4, stream);

    k_hist<<<RB, RT, 0, stream>>>(src, dst, histS, histD, E, chunk);
    k_scanA<<<2 * (RB / GRP) * 4, 256, 0, stream>>>(histS, histD, psumS, psumD);
    k_scanB<<<2, NBUCK, 0, stream>>>(psumS, baseS, grpbaseS, psumD, baseD, grpbaseD);
    k_bucket<<<RB, RT, 0, stream>>>(src, dst, histS, histD, grpbaseS, grpbaseD,
                                    tmpS, tmpD, E, chunk);
    k_fine<<<2 * nbuck_active, 256, 0, stream>>>(tmpD, baseD, csr_src, rowptr,
                                                 tmpS, baseS, degO, x, bufA, N, nbuck_active);

    k_spmm8<<<spmm8_blocks, 256, 0, stream>>>(bufA, rowptr, csr_src, bufB, N);
    k_gemm_reg<<<(N + 63) / 64, 64, 0, stream>>>(bufB, W1, b1, bufA, N);
    k_stats_fin<<<1024, 256, 0, stream>>>(bufA, sum1, sq1, g1, mu1, coef1, cnt1, N);
    k_bnrelu_scale<<<(n4 + 255) / 256, 256, 0, stream>>>((const float2*)bufA, mu1, coef1, be1,
                                                         degO, (float2*)bufB, n4);
    k_spmm8<<<spmm8_blocks, 256, 0, stream>>>(bufB, rowptr, csr_src, bufA, N);
    k_gemm_reg<<<(N + 63) / 64, 64, 0, stream>>>(bufA, W2, b2, bufB, N);
    k_stats_fin<<<1024, 256, 0, stream>>>(bufB, sum2, sq2, g2, mu2, coef2, cnt2, N);
    k_bnmean_fin<<<1024, 256, 0, stream>>>(bufB, mu2, coef2, be2, hsum, Wc, bc, out, cnt3, N);
}

// Round 12
// 304.630 us; speedup vs baseline: 1.5005x; 1.3117x over previous
//
#include <hip/hip_runtime.h>
#include <hip/hip_fp16.h>

#define FDIM 64
#define EPS 1e-5f
#define NBUCK 1024     // coarse buckets = high bits of 17-bit id
#define LOWB 7
#define LOWMASK 127
#define RB 256         // radix blocks
#define RT 1024        // radix threads per block
#define GRP 16         // rows per scan group (RB/GRP groups)
#define NSLOT 8        // accumulator slots to spread atomic RMW lines

// ---------------- per-block coarse histograms of src>>7 and dst>>7 ----------------
__global__ void k_hist(const int* __restrict__ src, const int* __restrict__ dst,
                       int* __restrict__ histS, int* __restrict__ histD, int E, int chunk) {
    __shared__ int hs[NBUCK], hd[NBUCK];
    int tid = threadIdx.x;            // RT == NBUCK == 1024
    hs[tid] = 0; hd[tid] = 0;
    __syncthreads();
    int b = blockIdx.x;
    int beg = b * chunk;
    int end = min(E, beg + chunk);
    int i = beg + tid * 4;
    for (; i + 3 < end; i += RT * 4) {
        int4 s = *(const int4*)(src + i);
        int4 d = *(const int4*)(dst + i);
        atomicAdd(&hs[s.x >> LOWB], 1); atomicAdd(&hd[d.x >> LOWB], 1);
        atomicAdd(&hs[s.y >> LOWB], 1); atomicAdd(&hd[d.y >> LOWB], 1);
        atomicAdd(&hs[s.z >> LOWB], 1); atomicAdd(&hd[d.z >> LOWB], 1);
        atomicAdd(&hs[s.w >> LOWB], 1); atomicAdd(&hd[d.w >> LOWB], 1);
    }
    if (i < end) {
        for (int j = i; j < end && j < i + 4; ++j) {
            atomicAdd(&hs[src[j] >> LOWB], 1);
            atomicAdd(&hd[dst[j] >> LOWB], 1);
        }
    }
    __syncthreads();
    histS[b * NBUCK + tid] = hs[tid];
    histD[b * NBUCK + tid] = hd[tid];
}

// ---------------- scan A: per-group column partial sums (fully parallel) ----------------
__global__ void k_scanA(const int* __restrict__ histS, const int* __restrict__ histD,
                        int* __restrict__ psumS, int* __restrict__ psumD) {
    int bid = blockIdx.x;
    int m = bid >> 6;                 // 0 = S, 1 = D
    int g = (bid >> 2) & (RB / GRP - 1);
    int c = bid & 3;
    const int* hist = m ? histD : histS;
    int* psum = m ? psumD : psumS;
    int k = c * 256 + threadIdx.x;
    int s = 0;
#pragma unroll
    for (int r = 0; r < GRP; ++r)
        s += hist[(g * GRP + r) * NBUCK + k];
    psum[g * NBUCK + k] = s;
}

// ---------------- scan B: group-level scan + bucket-base scan ----------------
__global__ void k_scanB(const int* __restrict__ psumS, int* __restrict__ baseS,
                        int* __restrict__ grpbaseS,
                        const int* __restrict__ psumD, int* __restrict__ baseD,
                        int* __restrict__ grpbaseD) {
    const int* psum = blockIdx.x ? psumD : psumS;
    int* base    = blockIdx.x ? baseD : baseS;
    int* grpbase = blockIdx.x ? grpbaseD : grpbaseS;
    __shared__ int s[NBUCK];
    int k = threadIdx.x;
    int ge[RB / GRP];
    int run = 0;
#pragma unroll
    for (int g = 0; g < RB / GRP; ++g) { ge[g] = run; run += psum[g * NBUCK + k]; }
    s[k] = run;
    __syncthreads();
    for (int off = 1; off < NBUCK; off <<= 1) {
        int t = (k >= off) ? s[k - off] : 0;
        __syncthreads();
        s[k] += t;
        __syncthreads();
    }
    int excl = (k > 0) ? s[k - 1] : 0;
    base[k] = excl;
    if (k == NBUCK - 1) base[NBUCK] = s[NBUCK - 1];
#pragma unroll
    for (int g = 0; g < RB / GRP; ++g)
        grpbase[g * NBUCK + k] = excl + ge[g];
}

// ---------------- coarse partition: LDS cursors per block, no global atomics ----------------
__global__ void k_bucket(const int* __restrict__ src, const int* __restrict__ dst,
                         const int* __restrict__ histS, const int* __restrict__ histD,
                         const int* __restrict__ grpbaseS, const int* __restrict__ grpbaseD,
                         unsigned char* __restrict__ tmpS, int* __restrict__ tmpD,
                         int E, int chunk) {
    __shared__ int curS[NBUCK], curD[NBUCK];
    int tid = threadIdx.x;
    int b = blockIdx.x;
    int g = b / GRP;
    int rs = 0, rd = 0;
    for (int r = g * GRP; r < b; ++r) {
        rs += histS[r * NBUCK + tid];
        rd += histD[r * NBUCK + tid];
    }
    curS[tid] = grpbaseS[g * NBUCK + tid] + rs;
    curD[tid] = grpbaseD[g * NBUCK + tid] + rd;
    __syncthreads();
    int beg = b * chunk;
    int end = min(E, beg + chunk);
    int i = beg + tid * 4;
    for (; i + 3 < end; i += RT * 4) {
        int4 s = *(const int4*)(src + i);
        int4 d = *(const int4*)(dst + i);
        int p;
        p = atomicAdd(&curS[s.x >> LOWB], 1); tmpS[p] = (unsigned char)(s.x & LOWMASK);
        p = atomicAdd(&curS[s.y >> LOWB], 1); tmpS[p] = (unsigned char)(s.y & LOWMASK);
        p = atomicAdd(&curS[s.z >> LOWB], 1); tmpS[p] = (unsigned char)(s.z & LOWMASK);
        p = atomicAdd(&curS[s.w >> LOWB], 1); tmpS[p] = (unsigned char)(s.w & LOWMASK);
        p = atomicAdd(&curD[d.x >> LOWB], 1); tmpD[p] = (s.x << LOWB) | (d.x & LOWMASK);
        p = atomicAdd(&curD[d.y >> LOWB], 1); tmpD[p] = (s.y << LOWB) | (d.y & LOWMASK);
        p = atomicAdd(&curD[d.z >> LOWB], 1); tmpD[p] = (s.z << LOWB) | (d.z & LOWMASK);
        p = atomicAdd(&curD[d.w >> LOWB], 1); tmpD[p] = (s.w << LOWB) | (d.w & LOWMASK);
    }
    if (i < end) {
        for (int j = i; j < end && j < i + 4; ++j) {
            int sv = src[j], dv = dst[j];
            int p = atomicAdd(&curS[sv >> LOWB], 1);
            tmpS[p] = (unsigned char)(sv & LOWMASK);
            p = atomicAdd(&curD[dv >> LOWB], 1);
            tmpD[p] = (sv << LOWB) | (dv & LOWMASK);
        }
    }
}

// ---------------- merged fine pass (one dispatch, two jobs running concurrently) ------
__global__ void k_fine(const int* __restrict__ tmpD, const int* __restrict__ baseD,
                       int* __restrict__ csr_src, int* __restrict__ rowptr,
                       const unsigned char* __restrict__ tmpS, const int* __restrict__ baseS,
                       int* __restrict__ degO, const float* __restrict__ x,
                       __half* __restrict__ bufA, int N, int nbuck) {
    __shared__ int hist[128];
    __shared__ int scanv[128];
    int tid = threadIdx.x;
    if (blockIdx.x < nbuck) {
        int b = blockIdx.x;
        int s0 = baseD[b];
        int s1 = baseD[b + 1];
        if (tid < 128) hist[tid] = 0;
        __syncthreads();
        for (int i = s0 + tid; i < s1; i += 256)
            atomicAdd(&hist[tmpD[i] & LOWMASK], 1);
        __syncthreads();
        int mine = (tid < 128) ? hist[tid] : 0;
        if (tid < 128) scanv[tid] = mine;
        __syncthreads();
        for (int off = 1; off < 128; off <<= 1) {
            int t = (tid < 128 && tid >= off) ? scanv[tid - off] : 0;
            __syncthreads();
            if (tid < 128) scanv[tid] += t;
            __syncthreads();
        }
        if (tid < 128) {
            int excl = scanv[tid] - mine;       // exclusive scan
            int d = (b << LOWB) + tid;
            if (d <= N) rowptr[d] = s0 + excl;  // covers rowptr[N]=E too
            hist[tid] = excl;                   // LDS cursors
        }
        __syncthreads();
        for (int i = s0 + tid; i < s1; i += 256) {
            int p = tmpD[i];
            int pos = atomicAdd(&hist[p & LOWMASK], 1);
            csr_src[s0 + pos] = p >> LOWB;
        }
    } else {
        int b = blockIdx.x - nbuck;
        int s0 = baseS[b];
        int s1 = baseS[b + 1];
        if (tid < 128) hist[tid] = 0;
        __syncthreads();
        for (int i = s0 + tid; i < s1; i += 256)
            atomicAdd(&hist[tmpS[i]], 1);
        __syncthreads();
        if (tid < 128) {
            int d = (b << LOWB) + tid;
            if (d < N) degO[d] = hist[tid];
        }
        // scale x rows for this bucket's 128 nodes: thread = (node, half-row part)
        int node = (b << LOWB) + (tid >> 1);
        if (node < N) {
            float rs = rsqrtf((float)max(hist[tid >> 1], 1));
            int part = tid & 1;                 // feats [part*32, part*32+32)
            const float4* xr = (const float4*)(x + (size_t)node * FDIM) + part * 8;
            float4* orow = (float4*)(bufA + (size_t)node * FDIM) + part * 4;
#pragma unroll
            for (int q = 0; q < 4; ++q) {
                float4 a = xr[2 * q];
                float4 c = xr[2 * q + 1];
                union { __half2 h[4]; float4 f; } u;
                u.h[0] = __floats2half2_rn(a.x * rs, a.y * rs);
                u.h[1] = __floats2half2_rn(a.z * rs, a.w * rs);
                u.h[2] = __floats2half2_rn(c.x * rs, c.y * rs);
                u.h[3] = __floats2half2_rn(c.z * rs, c.w * rs);
                orow[q] = u.f;
            }
        }
    }
}

// ---------------- CSR SpMM: 8 rows per wave, 16B/lane slices, fp32 acc ----------------
__global__ void k_spmm8(const __half* __restrict__ hin, const int* __restrict__ rowptr,
                        const int* __restrict__ csr_src, __half* __restrict__ out, int N) {
    int wid = (blockIdx.x * blockDim.x + threadIdx.x) >> 6;
    int lane = threadIdx.x & 63;
    int g = lane >> 3;
    int sl = lane & 7;
    int row = wid * 8 + g;
    bool rv = row < N;
    int start = rv ? rowptr[row] : 0;
    int end   = rv ? rowptr[row + 1] : 0;
    int deg = end - start;
    int md = deg;
    md = max(md, __shfl_xor(md, 8));
    md = max(md, __shfl_xor(md, 16));
    md = max(md, __shfl_xor(md, 32));
    float acc[8] = {0.f, 0.f, 0.f, 0.f, 0.f, 0.f, 0.f, 0.f};
    for (int it = 0; it < md; it += 8) {
        int a = start + it + sl;
        int ca = (a < end) ? a : ((deg > 0) ? end - 1 : 0);
        int idxv = csr_src[ca];
#pragma unroll
        for (int j = 0; j < 8; ++j) {
            int bidx = __shfl(idxv, (g << 3) + j);
            if (it + j < deg) {
                const float4* gp = (const float4*)(hin + ((size_t)bidx << 6));
                union { float4 f; __half2 h[4]; } u;
                u.f = gp[sl];
                float2 p0 = __half22float2(u.h[0]);
                float2 p1 = __half22float2(u.h[1]);
                float2 p2 = __half22float2(u.h[2]);
                float2 p3 = __half22float2(u.h[3]);
                acc[0] += p0.x; acc[1] += p0.y;
                acc[2] += p1.x; acc[3] += p1.y;
                acc[4] += p2.x; acc[5] += p2.y;
                acc[6] += p3.x; acc[7] += p3.y;
            }
        }
    }
    if (rv) {
        float rs = rsqrtf(fmaxf((float)deg, 1.0f));
        union { float4 f; __half2 h[4]; } o;
        o.h[0] = __floats2half2_rn(acc[0] * rs, acc[1] * rs);
        o.h[1] = __floats2half2_rn(acc[2] * rs, acc[3] * rs);
        o.h[2] = __floats2half2_rn(acc[4] * rs, acc[5] * rs);
        o.h[3] = __floats2half2_rn(acc[6] * rs, acc[7] * rs);
        ((float4*)(out + ((size_t)row << 6)))[sl] = o.f;
    }
}

// ---------------- register GEMM: 1 thread = 1 node; fp16 m in, fp16 h out, fp32 math ------
__global__ void k_gemm_reg(const __half* __restrict__ m, const float* __restrict__ W,
                           const float* __restrict__ b, __half* __restrict__ out, int N) {
    int n = blockIdx.x * blockDim.x + threadIdx.x;
    if (n >= N) return;
    const __half2* mrow = (const __half2*)(m + (size_t)n * FDIM);
    float acc[FDIM];
#pragma unroll
    for (int j = 0; j < FDIM; ++j) acc[j] = b[j];        // b[j] wave-uniform -> s_load
    for (int k0 = 0; k0 < FDIM; k0 += 8) {
        float2 f0 = __half22float2(mrow[(k0 >> 1) + 0]);
        float2 f1 = __half22float2(mrow[(k0 >> 1) + 1]);
        float2 f2 = __half22float2(mrow[(k0 >> 1) + 2]);
        float2 f3 = __half22float2(mrow[(k0 >> 1) + 3]);
        float mreg[8] = {f0.x, f0.y, f1.x, f1.y, f2.x, f2.y, f3.x, f3.y};
#pragma unroll
        for (int k1 = 0; k1 < 8; ++k1) {
            const float* Wrow = W + (k0 + k1) * FDIM;    // wave-uniform row -> s_load
#pragma unroll
            for (int j = 0; j < FDIM; ++j)
                acc[j] = fmaf(mreg[k1], Wrow[j], acc[j]);
        }
    }
    float4* orow = (float4*)(out + (size_t)n * FDIM);
#pragma unroll
    for (int j = 0; j < FDIM; j += 8) {
        union { __half2 h[4]; float4 f; } u;
        u.h[0] = __floats2half2_rn(acc[j + 0], acc[j + 1]);
        u.h[1] = __floats2half2_rn(acc[j + 2], acc[j + 3]);
        u.h[2] = __floats2half2_rn(acc[j + 4], acc[j + 5]);
        u.h[3] = __floats2half2_rn(acc[j + 6], acc[j + 7]);
        orow[j >> 3] = u.f;
    }
}

// ---------------- BN stats: slot-spread atomics + last-block finalize ----------------
// ssum/ssq are [NSLOT][64]; block adds into slot blockIdx&(NSLOT-1) -> 8x fewer RMW
// per cache line, lines processed in parallel across L2 banks.
__global__ void k_stats_fin(const __half* __restrict__ h, float* __restrict__ ssum,
                            float* __restrict__ ssq, const float* __restrict__ g,
                            float* __restrict__ mu, float* __restrict__ coef,
                            int* __restrict__ cnt, int N) {
    __shared__ float red[4][128];
    __shared__ int lastv;
    int tid = threadIdx.x;
    int sl = tid & 7;
    int nl = tid >> 3;
    float s[8] = {0.f,0.f,0.f,0.f,0.f,0.f,0.f,0.f};
    float q[8] = {0.f,0.f,0.f,0.f,0.f,0.f,0.f,0.f};
    int stride = gridDim.x * 32;
    for (int n = blockIdx.x * 32 + nl; n < N; n += stride) {
        union { float4 f; __half2 hh[4]; } u;
        u.f = ((const float4*)(h + ((size_t)n << 6)))[sl];
#pragma unroll
        for (int p = 0; p < 4; ++p) {
            float2 v = __half22float2(u.hh[p]);
            s[2*p]   += v.x; q[2*p]   += v.x * v.x;
            s[2*p+1] += v.y; q[2*p+1] += v.y * v.y;
        }
    }
#pragma unroll
    for (int off = 8; off < 64; off <<= 1) {
#pragma unroll
        for (int p = 0; p < 8; ++p) {
            s[p] += __shfl_xor(s[p], off);
            q[p] += __shfl_xor(q[p], off);
        }
    }
    int wv = tid >> 6, lane = tid & 63;
    if (lane < 8) {
#pragma unroll
        for (int p = 0; p < 8; ++p) {
            red[wv][lane * 8 + p] = s[p];
            red[wv][64 + lane * 8 + p] = q[p];
        }
    }
    __syncthreads();
    int slot = (blockIdx.x & (NSLOT - 1)) << 6;
    if (tid < 128) {
        float v = red[0][tid] + red[1][tid] + red[2][tid] + red[3][tid];
        if (tid < 64) atomicAdd(&ssum[slot + tid], v);
        else          atomicAdd(&ssq[slot + tid - 64], v);
    }
    __syncthreads();
    if (tid == 0)
        lastv = (__hip_atomic_fetch_add(cnt, 1, __ATOMIC_ACQ_REL,
                                        __HIP_MEMORY_SCOPE_AGENT) == (int)gridDim.x - 1);
    __syncthreads();
    if (lastv && tid < 64) {
        float sv = 0.f, qv = 0.f;
#pragma unroll
        for (int p = 0; p < NSLOT; ++p) {
            sv += __hip_atomic_load(&ssum[(p << 6) + tid], __ATOMIC_RELAXED,
                                    __HIP_MEMORY_SCOPE_AGENT);
            qv += __hip_atomic_load(&ssq[(p << 6) + tid], __ATOMIC_RELAXED,
                                    __HIP_MEMORY_SCOPE_AGENT);
        }
        float m = sv / (float)N;
        float var = qv / (float)N - m * m;
        mu[tid] = m;
        coef[tid] = rsqrtf(var + EPS) * g[tid];
    }
}

// ---------------- out = half(relu((h-mu)*coef+be) * rsqrt(max(degO,1))) ----------------
__global__ void k_bnrelu_scale(const float2* __restrict__ h, const float* __restrict__ mu,
                               const float* __restrict__ coef, const float* __restrict__ be,
                               const int* __restrict__ degO, float2* __restrict__ out, int n4) {
    int i = blockIdx.x * blockDim.x + threadIdx.x;
    if (i < n4) {
        int n = i >> 4;
        int j4 = (i & 15) << 2;
        float rs = rsqrtf((float)max(degO[n], 1));
        union { __half2 hh[2]; float2 f; } u;
        u.f = h[i];
        float2 v0 = __half22float2(u.hh[0]);
        float2 v1 = __half22float2(u.hh[1]);
        float r0 = fmaxf((v0.x - mu[j4 + 0]) * coef[j4 + 0] + be[j4 + 0], 0.f) * rs;
        float r1 = fmaxf((v0.y - mu[j4 + 1]) * coef[j4 + 1] + be[j4 + 1], 0.f) * rs;
        float r2 = fmaxf((v1.x - mu[j4 + 2]) * coef[j4 + 2] + be[j4 + 2], 0.f) * rs;
        float r3 = fmaxf((v1.y - mu[j4 + 3]) * coef[j4 + 3] + be[j4 + 3], 0.f) * rs;
        union { __half2 hh[2]; float2 f; } o;
        o.hh[0] = __floats2half2_rn(r0, r1);
        o.hh[1] = __floats2half2_rn(r2, r3);
        out[i] = o.f;
    }
}

// ---------------- relu(bn(h)) channel-sum (slot-spread) + last-block classifier -------
__global__ void k_bnmean_fin(const __half* __restrict__ h, const float* __restrict__ mu,
                             const float* __restrict__ coef, const float* __restrict__ be,
                             float* __restrict__ hsum, const float* __restrict__ Wc,
                             const float* __restrict__ bc, float* __restrict__ out,
                             int* __restrict__ cnt, int N) {
    __shared__ float red[4][64];
    __shared__ float cls[128];
    __shared__ int lastv;
    int tid = threadIdx.x;
    int sl = tid & 7;
    int nl = tid >> 3;
    int j8 = sl * 8;
    float m_[8], c_[8], b_[8];
#pragma unroll
    for (int p = 0; p < 8; ++p) { m_[p] = mu[j8 + p]; c_[p] = coef[j8 + p]; b_[p] = be[j8 + p]; }
    float s[8] = {0.f,0.f,0.f,0.f,0.f,0.f,0.f,0.f};
    int stride = gridDim.x * 32;
    for (int n = blockIdx.x * 32 + nl; n < N; n += stride) {
        union { float4 f; __half2 hh[4]; } u;
        u.f = ((const float4*)(h + ((size_t)n << 6)))[sl];
#pragma unroll
        for (int p = 0; p < 4; ++p) {
            float2 v = __half22float2(u.hh[p]);
            s[2*p]   += fmaxf((v.x - m_[2*p])   * c_[2*p]   + b_[2*p],   0.f);
            s[2*p+1] += fmaxf((v.y - m_[2*p+1]) * c_[2*p+1] + b_[2*p+1], 0.f);
        }
    }
#pragma unroll
    for (int off = 8; off < 64; off <<= 1) {
#pragma unroll
        for (int p = 0; p < 8; ++p) s[p] += __shfl_xor(s[p], off);
    }
    int wv = tid >> 6, lane = tid & 63;
    if (lane < 8) {
#pragma unroll
        for (int p = 0; p < 8; ++p) red[wv][lane * 8 + p] = s[p];
    }
    __syncthreads();
    int slot = (blockIdx.x & (NSLOT - 1)) << 6;
    if (tid < 64)
        atomicAdd(&hsum[slot + tid], red[0][tid] + red[1][tid] + red[2][tid] + red[3][tid]);
    __syncthreads();
    if (tid == 0)
        lastv = (__hip_atomic_fetch_add(cnt, 1, __ATOMIC_ACQ_REL,
                                        __HIP_MEMORY_SCOPE_AGENT) == (int)gridDim.x - 1);
    __syncthreads();
    if (lastv) {
        if (tid < 64) {
            float hg = 0.f;
#pragma unroll
            for (int p = 0; p < NSLOT; ++p)
                hg += __hip_atomic_load(&hsum[(p << 6) + tid], __ATOMIC_RELAXED,
                                        __HIP_MEMORY_SCOPE_AGENT);
            hg /= (float)N;
            cls[tid]      = hg * Wc[tid * 2 + 0];
            cls[64 + tid] = hg * Wc[tid * 2 + 1];
        }
        __syncthreads();
        if (tid == 0) {
            float a = 0.f, bv = 0.f;
            for (int k = 0; k < 64; ++k) { a += cls[k]; bv += cls[64 + k]; }
            out[0] = a + bc[0];
            out[1] = bv + bc[1];
        }
    }
}

extern "C" void kernel_launch(void* const* d_in, const int* in_sizes, int n_in,
                              void* d_out, int out_size, void* d_ws, size_t ws_size,
                              hipStream_t stream) {
    const float* x   = (const float*)d_in[0];
    const int*   src = (const int*)d_in[1];
    const int*   dst = (const int*)d_in[2];
    const float* W1  = (const float*)d_in[3];
    const float* b1  = (const float*)d_in[4];
    const float* g1  = (const float*)d_in[5];
    const float* be1 = (const float*)d_in[6];
    const float* W2  = (const float*)d_in[7];
    const float* b2  = (const float*)d_in[8];
    const float* g2  = (const float*)d_in[9];
    const float* be2 = (const float*)d_in[10];
    const float* Wc  = (const float*)d_in[11];
    const float* bc  = (const float*)d_in[12];
    float* out = (float*)d_out;

    const int N = in_sizes[0] / FDIM;   // 100000
    const int E = in_sizes[1];          // 1600000

    // ---- workspace layout ----
    char* w = (char*)d_ws;
    __half* bufA   = (__half*)w;                                  // N*64 halfs (12.8 MB)
    __half* bufB   = bufA + (size_t)N * FDIM;                     // N*64 halfs
    int*   csr_src = (int*)(bufB + (size_t)N * FDIM);             // E int
    int*   degO    = csr_src + E;                                 // N int
    int*   rowptr  = degO + N;                                    // N+2 int
    int*   histS   = rowptr + N + 2;                              // RB*NBUCK int
    int*   histD   = histS + RB * NBUCK;                          // RB*NBUCK int
    int*   baseS   = histD + RB * NBUCK;                          // NBUCK+1
    int*   baseD   = baseS + NBUCK + 1;                           // NBUCK+1
    int*   psumS   = baseD + NBUCK + 1;                           // (RB/GRP)*NBUCK
    int*   psumD   = psumS + (RB / GRP) * NBUCK;                  // (RB/GRP)*NBUCK
    int*   grpbaseS= psumD + (RB / GRP) * NBUCK;                  // (RB/GRP)*NBUCK
    int*   grpbaseD= grpbaseS + (RB / GRP) * NBUCK;               // (RB/GRP)*NBUCK
    float* stats   = (float*)(grpbaseD + (RB / GRP) * NBUCK);     // 4096 f } memset
    unsigned char* tmpS = (unsigned char*)(stats + 4096);         // E bytes (dedicated)
    int*           tmpD = (int*)bufB;                             // E int, aliases bufB (dead)

    float* sum1  = stats + 0;            // [NSLOT][64] = 512
    float* sq1   = stats + 512;          // 512
    float* sum2  = stats + 1024;         // 512
    float* sq2   = stats + 1536;         // 512
    float* hsum  = stats + 2048;         // 512
    float* mu1   = stats + 2560;
    float* coef1 = stats + 2624;
    float* mu2   = stats + 2688;
    float* coef2 = stats + 2752;
    int*   cnt1  = (int*)(stats + 2816);
    int*   cnt2  = (int*)(stats + 2817);
    int*   cnt3  = (int*)(stats + 2818);

    const int n4 = N * (FDIM / 4);
    const int spmm8_blocks = ((N + 7) / 8 + 3) / 4;       // 8 rows/wave, 4 waves/block
    const int nbuck_active = (N + LOWMASK) >> LOWB;       // 782 for N=100000
    const int chunk = ((E + RB - 1) / RB + 3) & ~3;       // per-block edges, mult of 4

    hipMemsetAsync(stats, 0, 4096 * 4, stream);

    k_hist<<<RB, RT, 0, stream>>>(src, dst, histS, histD, E, chunk);
    k_scanA<<<2 * (RB / GRP) * 4, 256, 0, stream>>>(histS, histD, psumS, psumD);
    k_scanB<<<2, NBUCK, 0, stream>>>(psumS, baseS, grpbaseS, psumD, baseD, grpbaseD);
    k_bucket<<<RB, RT, 0, stream>>>(src, dst, histS, histD, grpbaseS, grpbaseD,
                                    tmpS, tmpD, E, chunk);
    k_fine<<<2 * nbuck_active, 256, 0, stream>>>(tmpD, baseD, csr_src, rowptr,
                                                 tmpS, baseS, degO, x, bufA, N, nbuck_active);

    k_spmm8<<<spmm8_blocks, 256, 0, stream>>>(bufA, rowptr, csr_src, bufB, N);
    k_gemm_reg<<<(N + 63) / 64, 64, 0, stream>>>(bufB, W1, b1, bufA, N);
    k_stats_fin<<<256, 256, 0, stream>>>(bufA, sum1, sq1, g1, mu1, coef1, cnt1, N);
    k_bnrelu_scale<<<(n4 + 255) / 256, 256, 0, stream>>>((const float2*)bufA, mu1, coef1, be1,
                                                         degO, (float2*)bufB, n4);
    k_spmm8<<<spmm8_blocks, 256, 0, stream>>>(bufB, rowptr, csr_src, bufA, N);
    k_gemm_reg<<<(N + 63) / 64, 64, 0, stream>>>(bufA, W2, b2, bufB, N);
    k_stats_fin<<<256, 256, 0, stream>>>(bufB, sum2, sq2, g2, mu2, coef2, cnt2, N);
    k_bnmean_fin<<<256, 256, 0, stream>>>(bufB, mu2, coef2, be2, hsum, Wc, bc, out, cnt3, N);
}